// Round 1
// baseline (1672.423 us; speedup 1.0000x reference)
//
#include <hip/hip_runtime.h>
#include <hip/hip_bf16.h>

// ---------------- problem constants (match reference) ----------------
static constexpr int N_NODES = 100000;
static constexpr int N_EDGES = 3200000;
static constexpr int NFEAT   = 512;
static constexpr int NHID    = 256;
static constexpr int NCLASS  = 64;

static constexpr int SCAN_CHUNK = 2048;                       // 256 thr * 8 items
static constexpr int NB = (N_NODES + SCAN_CHUNK - 1) / SCAN_CHUNK; // 49

__device__ __forceinline__ float to_f32(float v) { return v; }
__device__ __forceinline__ float to_f32(__hip_bfloat16 v) { return __bfloat162float(v); }

// ---------------- CSR build ----------------
__global__ __launch_bounds__(256) void hist_kernel(const int* __restrict__ edst,
                                                   int* __restrict__ counts) {
    for (int e = blockIdx.x * blockDim.x + threadIdx.x; e < N_EDGES;
         e += gridDim.x * blockDim.x)
        atomicAdd(&counts[edst[e]], 1);
}

__global__ __launch_bounds__(256) void scan_part_kernel(const int* __restrict__ counts,
                                                        int* __restrict__ partials) {
    int b = blockIdx.x, t = threadIdx.x;
    int base = b * SCAN_CHUNK + t * 8;
    int s = 0;
#pragma unroll
    for (int j = 0; j < 8; ++j) {
        int i = base + j;
        if (i < N_NODES) s += counts[i];
    }
    __shared__ int sd[256];
    sd[t] = s;
    __syncthreads();
    for (int off = 128; off > 0; off >>= 1) {
        if (t < off) sd[t] += sd[t + off];
        __syncthreads();
    }
    if (t == 0) partials[b] = sd[0];
}

__global__ void scan_mid_kernel(int* __restrict__ partials) {
    if (threadIdx.x == 0) {
        int run = 0;
        for (int i = 0; i < NB; ++i) {
            int v = partials[i];
            partials[i] = run;
            run += v;
        }
    }
}

// counts and cursor alias the same buffer: read counts, write scanned value back.
__global__ __launch_bounds__(256) void scan_final_kernel(int* __restrict__ counts_cursor,
                                                         int* __restrict__ row_ptr,
                                                         const int* __restrict__ partials) {
    int b = blockIdx.x, t = threadIdx.x;
    int base = b * SCAN_CHUNK + t * 8;
    int v[8];
    int tsum = 0;
#pragma unroll
    for (int j = 0; j < 8; ++j) {
        int i = base + j;
        v[j] = (i < N_NODES) ? counts_cursor[i] : 0;
        tsum += v[j];
    }
    __shared__ int sd[256];
    sd[t] = tsum;
    __syncthreads();
    // Hillis-Steele inclusive scan
    for (int off = 1; off < 256; off <<= 1) {
        int x = (t >= off) ? sd[t - off] : 0;
        __syncthreads();
        sd[t] += x;
        __syncthreads();
    }
    int run = sd[t] - tsum + partials[b];  // exclusive prefix for this thread
#pragma unroll
    for (int j = 0; j < 8; ++j) {
        int i = base + j;
        if (i < N_NODES) {
            row_ptr[i] = run;
            counts_cursor[i] = run;  // cursor for the scatter pass
        }
        run += v[j];
    }
    if (b == 0 && t == 0) row_ptr[N_NODES] = N_EDGES;
}

__global__ __launch_bounds__(256) void scatter_kernel(const int* __restrict__ esrc,
                                                      const int* __restrict__ edst,
                                                      const float* __restrict__ ew,
                                                      int* __restrict__ cursor,
                                                      int* __restrict__ src_sorted,
                                                      float* __restrict__ w_sorted) {
    for (int e = blockIdx.x * blockDim.x + threadIdx.x; e < N_EDGES;
         e += gridDim.x * blockDim.x) {
        int d = edst[e];
        int pos = atomicAdd(&cursor[d], 1);
        src_sorted[pos] = esrc[e];
        w_sorted[pos]   = ew[e];
    }
}

// ---------------- tiled GEMM: C[M,N] = A[M,K] @ B[K,N], C stored bf16 ----------------
template <typename TA>
__global__ __launch_bounds__(256) void gemm_tiled(const TA* __restrict__ A,
                                                  const float* __restrict__ B,
                                                  __hip_bfloat16* __restrict__ C,
                                                  int M, int N, int K) {
    constexpr int BM = 64, BN = 64, BK = 32;
    __shared__ float As[BK][BM + 1];
    __shared__ float Bs[BK][BN + 1];
    int tid = threadIdx.x;
    int tx = tid & 15, ty = tid >> 4;  // 16x16 thread grid, 4x4 microtile
    int row0 = blockIdx.x * BM, col0 = blockIdx.y * BN;
    float acc[4][4] = {};
    for (int k0 = 0; k0 < K; k0 += BK) {
#pragma unroll
        for (int it = 0; it < 8; ++it) {  // A tile: BM x BK
            int l = tid + 256 * it;
            int r = l >> 5, c = l & 31;
            int gr = row0 + r;
            As[c][r] = (gr < M) ? to_f32(A[(size_t)gr * K + k0 + c]) : 0.f;
        }
#pragma unroll
        for (int it = 0; it < 8; ++it) {  // B tile: BK x BN
            int l = tid + 256 * it;
            int r = l >> 6, c = l & 63;
            Bs[r][c] = B[(size_t)(k0 + r) * N + col0 + c];
        }
        __syncthreads();
#pragma unroll
        for (int k = 0; k < BK; ++k) {
            float a[4], bb[4];
#pragma unroll
            for (int i = 0; i < 4; ++i) a[i] = As[k][ty * 4 + i];
#pragma unroll
            for (int i = 0; i < 4; ++i) bb[i] = Bs[k][tx * 4 + i];
#pragma unroll
            for (int i = 0; i < 4; ++i)
#pragma unroll
                for (int j = 0; j < 4; ++j) acc[i][j] += a[i] * bb[j];
        }
        __syncthreads();
    }
#pragma unroll
    for (int i = 0; i < 4; ++i) {
        int gr = row0 + ty * 4 + i;
        if (gr < M) {
#pragma unroll
            for (int j = 0; j < 4; ++j)
                C[(size_t)gr * N + col0 + tx * 4 + j] = __float2bfloat16(acc[i][j]);
        }
    }
}

// ---------------- SPMM layer1: Z0[dst,:256] = sum_e w * support0[src,:]; +b1, relu ----------------
__global__ __launch_bounds__(256) void spmm1_kernel(const __hip_bfloat16* __restrict__ support0,
                                                    const int* __restrict__ row_ptr,
                                                    const int* __restrict__ src_sorted,
                                                    const float* __restrict__ w_sorted,
                                                    const float* __restrict__ b1,
                                                    __hip_bfloat16* __restrict__ H0) {
    int d = blockIdx.x;
    int t = threadIdx.x;
    int beg = row_ptr[d], end = row_ptr[d + 1];
    __shared__ int   s_src[256];
    __shared__ float s_w[256];
    float acc = 0.f;
    for (int base = beg; base < end; base += 256) {
        int m = min(256, end - base);
        __syncthreads();
        if (t < m) {
            s_src[t] = src_sorted[base + t];
            s_w[t]   = w_sorted[base + t];
        }
        __syncthreads();
        for (int j = 0; j < m; ++j) {
            acc += s_w[j] * to_f32(support0[(size_t)s_src[j] * NHID + t]);
        }
    }
    float z = acc + b1[t];
    z = fmaxf(z, 0.f);
    H0[(size_t)d * NHID + t] = __float2bfloat16(z);
}

// ---------------- SPMM layer2 + bias + log_softmax (one wave per node) ----------------
__global__ __launch_bounds__(256) void spmm2_softmax_kernel(const __hip_bfloat16* __restrict__ support1,
                                                            const int* __restrict__ row_ptr,
                                                            const int* __restrict__ src_sorted,
                                                            const float* __restrict__ w_sorted,
                                                            const float* __restrict__ b2,
                                                            float* __restrict__ out) {
    int node = blockIdx.x * 4 + (threadIdx.x >> 6);
    int lane = threadIdx.x & 63;
    if (node >= N_NODES) return;
    int beg = row_ptr[node], end = row_ptr[node + 1];
    float acc = 0.f;
    for (int j = beg; j < end; ++j) {
        int s   = src_sorted[j];
        float w = w_sorted[j];
        acc += w * to_f32(support1[(size_t)s * NCLASS + lane]);
    }
    float z = acc + b2[lane];
    // log_softmax across the 64 lanes
    float m = z;
#pragma unroll
    for (int off = 32; off > 0; off >>= 1) m = fmaxf(m, __shfl_xor(m, off));
    float ex = __expf(z - m);
    float s = ex;
#pragma unroll
    for (int off = 32; off > 0; off >>= 1) s += __shfl_xor(s, off);
    out[(size_t)node * NCLASS + lane] = z - m - __logf(s);
}

// ---------------- host launch ----------------
extern "C" void kernel_launch(void* const* d_in, const int* in_sizes, int n_in,
                              void* d_out, int out_size, void* d_ws, size_t ws_size,
                              hipStream_t stream) {
    const float* x    = (const float*)d_in[0];
    const int*   esrc = (const int*)d_in[1];
    const int*   edst = (const int*)d_in[2];
    const float* ew   = (const float*)d_in[3];
    const float* W1   = (const float*)d_in[4];
    const float* b1   = (const float*)d_in[5];
    const float* W2   = (const float*)d_in[6];
    const float* b2   = (const float*)d_in[7];
    float* out = (float*)d_out;

    char* ws = (char*)d_ws;
    size_t off = 0;
    auto alloc = [&](size_t bytes) {
        size_t o = off;
        off = (off + bytes + 255) & ~(size_t)255;
        return o;
    };
    __hip_bfloat16* support0 = (__hip_bfloat16*)(ws + alloc((size_t)N_NODES * NHID * 2));
    __hip_bfloat16* H0       = (__hip_bfloat16*)(ws + alloc((size_t)N_NODES * NHID * 2));
    __hip_bfloat16* support1 = (__hip_bfloat16*)(ws + alloc((size_t)N_NODES * NCLASS * 2));
    int*   src_sorted = (int*)(ws + alloc((size_t)N_EDGES * 4));
    float* w_sorted   = (float*)(ws + alloc((size_t)N_EDGES * 4));
    int*   row_ptr    = (int*)(ws + alloc((size_t)(N_NODES + 1) * 4));
    int*   cursor     = (int*)(ws + alloc((size_t)N_NODES * 4));
    int*   partials   = (int*)(ws + alloc(256 * 4));

    // --- CSR build ---
    hipMemsetAsync(cursor, 0, (size_t)N_NODES * 4, stream);
    hist_kernel<<<2048, 256, 0, stream>>>(edst, cursor);
    scan_part_kernel<<<NB, 256, 0, stream>>>(cursor, partials);
    scan_mid_kernel<<<1, 64, 0, stream>>>(partials);
    scan_final_kernel<<<NB, 256, 0, stream>>>(cursor, row_ptr, partials);
    scatter_kernel<<<2048, 256, 0, stream>>>(esrc, edst, ew, cursor, src_sorted, w_sorted);

    // --- Layer 1: GEMM1 (x @ W1 -> bf16), SPMM1 (+b1, relu) ---
    gemm_tiled<float><<<dim3((N_NODES + 63) / 64, NHID / 64), 256, 0, stream>>>(
        x, W1, support0, N_NODES, NHID, NFEAT);
    spmm1_kernel<<<N_NODES, 256, 0, stream>>>(support0, row_ptr, src_sorted, w_sorted, b1, H0);

    // --- Layer 2: GEMM2 (H0 @ W2 -> bf16), SPMM2 + bias + log_softmax ---
    gemm_tiled<__hip_bfloat16><<<dim3((N_NODES + 63) / 64, NCLASS / 64), 256, 0, stream>>>(
        H0, W2, support1, N_NODES, NCLASS, NHID);
    spmm2_softmax_kernel<<<N_NODES / 4, 256, 0, stream>>>(support1, row_ptr, src_sorted,
                                                          w_sorted, b2, out);
}

// Round 2
// 1030.517 us; speedup vs baseline: 1.6229x; 1.6229x over previous
//
#include <hip/hip_runtime.h>
#include <hip/hip_bf16.h>

// ---------------- problem constants (match reference) ----------------
static constexpr int N_NODES = 100000;
static constexpr int N_EDGES = 3200000;
static constexpr int NFEAT   = 512;
static constexpr int NHID    = 256;
static constexpr int NCLASS  = 64;

static constexpr int SCAN_CHUNK = 2048;                       // 256 thr * 8 items
static constexpr int NB = (N_NODES + SCAN_CHUNK - 1) / SCAN_CHUNK; // 49

using short8 = __attribute__((ext_vector_type(8))) short;
using f32x4  = __attribute__((ext_vector_type(4))) float;
using fv4    = __attribute__((ext_vector_type(4))) float;

__device__ __forceinline__ float to_f32(float v) { return v; }
__device__ __forceinline__ float to_f32(__hip_bfloat16 v) { return __bfloat162float(v); }

__device__ __forceinline__ short f2bf_bits(float f) {
    __hip_bfloat16 h = __float2bfloat16(f);
    return *reinterpret_cast<short*>(&h);
}

#define GLOBAL_TO_LDS(gsrc, ldst)                                                        \
    __builtin_amdgcn_global_load_lds((const __attribute__((address_space(1))) void*)(gsrc), \
                                     (__attribute__((address_space(3))) void*)(ldst), 16, 0, 0)

// ---------------- CSR build ----------------
__global__ __launch_bounds__(256) void hist_kernel(const int* __restrict__ edst,
                                                   int* __restrict__ counts) {
    for (int e = blockIdx.x * blockDim.x + threadIdx.x; e < N_EDGES;
         e += gridDim.x * blockDim.x)
        atomicAdd(&counts[edst[e]], 1);
}

__global__ __launch_bounds__(256) void scan_part_kernel(const int* __restrict__ counts,
                                                        int* __restrict__ partials) {
    int b = blockIdx.x, t = threadIdx.x;
    int base = b * SCAN_CHUNK + t * 8;
    int s = 0;
#pragma unroll
    for (int j = 0; j < 8; ++j) {
        int i = base + j;
        if (i < N_NODES) s += counts[i];
    }
    __shared__ int sd[256];
    sd[t] = s;
    __syncthreads();
    for (int off = 128; off > 0; off >>= 1) {
        if (t < off) sd[t] += sd[t + off];
        __syncthreads();
    }
    if (t == 0) partials[b] = sd[0];
}

__global__ void scan_mid_kernel(int* __restrict__ partials) {
    if (threadIdx.x == 0) {
        int run = 0;
        for (int i = 0; i < NB; ++i) {
            int v = partials[i];
            partials[i] = run;
            run += v;
        }
    }
}

__global__ __launch_bounds__(256) void scan_final_kernel(int* __restrict__ counts_cursor,
                                                         int* __restrict__ row_ptr,
                                                         const int* __restrict__ partials) {
    int b = blockIdx.x, t = threadIdx.x;
    int base = b * SCAN_CHUNK + t * 8;
    int v[8];
    int tsum = 0;
#pragma unroll
    for (int j = 0; j < 8; ++j) {
        int i = base + j;
        v[j] = (i < N_NODES) ? counts_cursor[i] : 0;
        tsum += v[j];
    }
    __shared__ int sd[256];
    sd[t] = tsum;
    __syncthreads();
    for (int off = 1; off < 256; off <<= 1) {
        int x = (t >= off) ? sd[t - off] : 0;
        __syncthreads();
        sd[t] += x;
        __syncthreads();
    }
    int run = sd[t] - tsum + partials[b];
#pragma unroll
    for (int j = 0; j < 8; ++j) {
        int i = base + j;
        if (i < N_NODES) {
            row_ptr[i] = run;
            counts_cursor[i] = run;
        }
        run += v[j];
    }
    if (b == 0 && t == 0) row_ptr[N_NODES] = N_EDGES;
}

__global__ __launch_bounds__(256) void scatter_kernel(const int* __restrict__ esrc,
                                                      const int* __restrict__ edst,
                                                      const float* __restrict__ ew,
                                                      int* __restrict__ cursor,
                                                      int* __restrict__ src_sorted,
                                                      float* __restrict__ w_sorted) {
    for (int e = blockIdx.x * blockDim.x + threadIdx.x; e < N_EDGES;
         e += gridDim.x * blockDim.x) {
        int d = edst[e];
        int pos = atomicAdd(&cursor[d], 1);
        src_sorted[pos] = esrc[e];
        w_sorted[pos]   = ew[e];
    }
}

// ---------------- small transpose+cast: W[K][N] f32 -> WT[N][K] bf16 ----------------
__global__ __launch_bounds__(256) void transpose_w_kernel(const float* __restrict__ W,
                                                          __hip_bfloat16* __restrict__ WT,
                                                          int K, int N) {
    int idx = blockIdx.x * 256 + threadIdx.x;
    if (idx < K * N) {
        int k = idx / N, n = idx % N;
        WT[(size_t)n * K + k] = __float2bfloat16(W[idx]);
    }
}

// ---------------- GEMM1: C[M,256] = A[M,512](f32) @ W1T[256,512](bf16)^T, C bf16 ----
// 128x128 tile, 4 waves (2x2), 4x4 fragments of 16x16x32 MFMA.
// A fragments loaded straight from global (fp32 -> bf16 in reg).
// B tile [128][32] bf16 staged per K-step via global_load_lds, XOR-swizzled.
__global__ __launch_bounds__(256) void gemm1_mfma(const float* __restrict__ A,
                                                  const __hip_bfloat16* __restrict__ BT,
                                                  __hip_bfloat16* __restrict__ C,
                                                  int M) {
    constexpr int K = NFEAT;   // 512
    constexpr int N = NHID;    // 256
    constexpr int BM = 128, BN = 128, BK = 32;
    __shared__ __align__(16) __hip_bfloat16 Bs[BN * BK];  // 8 KB
    const int tid = threadIdx.x;
    const int lane = tid & 63, wave = tid >> 6;
    const int wr = wave >> 1, wc = wave & 1;
    const int laneRow = lane & 15, laneK = lane >> 4;
    const int row0 = blockIdx.x * BM, col0 = blockIdx.y * BN;

    f32x4 acc[4][4] = {};

    int arow[4];
#pragma unroll
    for (int i = 0; i < 4; ++i) {
        int r = row0 + wr * 64 + i * 16 + laneRow;
        arow[i] = (r < M) ? r : (M - 1);
    }

    for (int k0 = 0; k0 < K; k0 += BK) {
        // stage B tile: 512 granules of 16B, swizzle gk ^= (n>>1)&3
#pragma unroll
        for (int it = 0; it < 2; ++it) {
            int idx = tid + it * 256;
            int n = idx >> 2;
            int gk = (idx & 3) ^ ((n >> 1) & 3);
            const __hip_bfloat16* src = BT + (size_t)(col0 + n) * K + k0 + gk * 8;
            GLOBAL_TO_LDS(src, Bs + (size_t)idx * 8);
        }
        // A fragments: 8 consecutive fp32 per lane -> bf16
        short8 af[4];
#pragma unroll
        for (int i = 0; i < 4; ++i) {
            const float* ap = A + (size_t)arow[i] * K + k0 + laneK * 8;
            fv4 a0 = *(const fv4*)ap;
            fv4 a1 = *(const fv4*)(ap + 4);
            short8 v;
#pragma unroll
            for (int j = 0; j < 4; ++j) v[j] = f2bf_bits(a0[j]);
#pragma unroll
            for (int j = 0; j < 4; ++j) v[4 + j] = f2bf_bits(a1[j]);
            af[i] = v;
        }
        __syncthreads();  // drains vmcnt: Bs ready (and A regs ready)
        short8 bfr[4];
#pragma unroll
        for (int j = 0; j < 4; ++j) {
            int n = wc * 64 + j * 16 + laneRow;
            int pg = laneK ^ ((n >> 1) & 3);
            bfr[j] = *(const short8*)(Bs + n * BK + pg * 8);
        }
#pragma unroll
        for (int i = 0; i < 4; ++i)
#pragma unroll
            for (int j = 0; j < 4; ++j)
                acc[i][j] = __builtin_amdgcn_mfma_f32_16x16x32_bf16(af[i], bfr[j], acc[i][j], 0, 0, 0);
        __syncthreads();  // protect Bs before next stage
    }
    // epilogue: C/D layout col=lane&15, row=(lane>>4)*4+q
#pragma unroll
    for (int i = 0; i < 4; ++i) {
        int rbase = row0 + wr * 64 + i * 16 + laneK * 4;
#pragma unroll
        for (int j = 0; j < 4; ++j) {
            int col = col0 + wc * 64 + j * 16 + laneRow;
#pragma unroll
            for (int q = 0; q < 4; ++q) {
                int row = rbase + q;
                if (row < M) C[(size_t)row * N + col] = __float2bfloat16(acc[i][j][q]);
            }
        }
    }
}

// ---------------- GEMM2: C[M,64] = A[M,256](bf16) @ W2T[64,256](bf16)^T, C bf16 ----
// Whole W2T lives in LDS (32 KB, swizzled); barrier-free K loop; A frags from global.
__global__ __launch_bounds__(256) void gemm2_mfma(const __hip_bfloat16* __restrict__ A,
                                                  const __hip_bfloat16* __restrict__ BT,
                                                  __hip_bfloat16* __restrict__ C,
                                                  int M) {
    constexpr int K = NHID;    // 256
    constexpr int N = NCLASS;  // 64
    constexpr int BM = 128;
    __shared__ __align__(16) __hip_bfloat16 Bs[N * K];  // 32 KB
    const int tid = threadIdx.x;
    const int lane = tid & 63, wave = tid >> 6;
    const int wr = wave >> 1, wc = wave & 1;
    const int laneRow = lane & 15, laneK = lane >> 4;
    const int row0 = blockIdx.x * BM;

    // stage all of BT: 2048 granules of 16B, swizzle kk ^= n&7
#pragma unroll
    for (int it = 0; it < 8; ++it) {
        int idx = tid + it * 256;
        int n = idx >> 5;
        int kk = (idx & 31) ^ (n & 7);
        const __hip_bfloat16* src = BT + (size_t)n * K + kk * 8;
        GLOBAL_TO_LDS(src, Bs + (size_t)idx * 8);
    }

    int arow[4];
#pragma unroll
    for (int i = 0; i < 4; ++i) {
        int r = row0 + wr * 64 + i * 16 + laneRow;
        arow[i] = (r < M) ? r : (M - 1);
    }

    f32x4 acc[4][2] = {};
    __syncthreads();  // Bs fully staged

#pragma unroll
    for (int k0 = 0; k0 < K; k0 += 32) {
        short8 af[4];
#pragma unroll
        for (int i = 0; i < 4; ++i)
            af[i] = *(const short8*)(A + (size_t)arow[i] * K + k0 + laneK * 8);
        short8 bfr[2];
#pragma unroll
        for (int j = 0; j < 2; ++j) {
            int n = wc * 32 + j * 16 + laneRow;
            int kkw = (k0 >> 3) + laneK;
            int pkk = kkw ^ (n & 7);
            bfr[j] = *(const short8*)(Bs + (size_t)n * 32 * 8 + pkk * 8);
        }
#pragma unroll
        for (int i = 0; i < 4; ++i)
#pragma unroll
            for (int j = 0; j < 2; ++j)
                acc[i][j] = __builtin_amdgcn_mfma_f32_16x16x32_bf16(af[i], bfr[j], acc[i][j], 0, 0, 0);
    }

#pragma unroll
    for (int i = 0; i < 4; ++i) {
        int rbase = row0 + wr * 64 + i * 16 + laneK * 4;
#pragma unroll
        for (int j = 0; j < 2; ++j) {
            int col = wc * 32 + j * 16 + laneRow;
#pragma unroll
            for (int q = 0; q < 4; ++q) {
                int row = rbase + q;
                if (row < M) C[(size_t)row * N + col] = __float2bfloat16(acc[i][j][q]);
            }
        }
    }
}

// ---------------- SPMM layer1: Z0[dst,:256] = sum_e w * support0[src,:]; +b1, relu ----
__global__ __launch_bounds__(256) void spmm1_kernel(const __hip_bfloat16* __restrict__ support0,
                                                    const int* __restrict__ row_ptr,
                                                    const int* __restrict__ src_sorted,
                                                    const float* __restrict__ w_sorted,
                                                    const float* __restrict__ b1,
                                                    __hip_bfloat16* __restrict__ H0) {
    int d = blockIdx.x;
    int t = threadIdx.x;
    int beg = row_ptr[d], end = row_ptr[d + 1];
    __shared__ int   s_src[256];
    __shared__ float s_w[256];
    float acc = 0.f;
    for (int base = beg; base < end; base += 256) {
        int m = min(256, end - base);
        __syncthreads();
        if (t < m) {
            s_src[t] = src_sorted[base + t];
            s_w[t]   = w_sorted[base + t];
        }
        __syncthreads();
        for (int j = 0; j < m; ++j) {
            acc += s_w[j] * to_f32(support0[(size_t)s_src[j] * NHID + t]);
        }
    }
    float z = acc + b1[t];
    z = fmaxf(z, 0.f);
    H0[(size_t)d * NHID + t] = __float2bfloat16(z);
}

// ---------------- SPMM layer2 + bias + log_softmax (one wave per node) ----------------
__global__ __launch_bounds__(256) void spmm2_softmax_kernel(const __hip_bfloat16* __restrict__ support1,
                                                            const int* __restrict__ row_ptr,
                                                            const int* __restrict__ src_sorted,
                                                            const float* __restrict__ w_sorted,
                                                            const float* __restrict__ b2,
                                                            float* __restrict__ out) {
    int node = blockIdx.x * 4 + (threadIdx.x >> 6);
    int lane = threadIdx.x & 63;
    if (node >= N_NODES) return;
    int beg = row_ptr[node], end = row_ptr[node + 1];
    float acc = 0.f;
    for (int j = beg; j < end; ++j) {
        int s   = src_sorted[j];
        float w = w_sorted[j];
        acc += w * to_f32(support1[(size_t)s * NCLASS + lane]);
    }
    float z = acc + b2[lane];
    float m = z;
#pragma unroll
    for (int off = 32; off > 0; off >>= 1) m = fmaxf(m, __shfl_xor(m, off));
    float ex = __expf(z - m);
    float s = ex;
#pragma unroll
    for (int off = 32; off > 0; off >>= 1) s += __shfl_xor(s, off);
    out[(size_t)node * NCLASS + lane] = z - m - __logf(s);
}

// ---------------- host launch ----------------
extern "C" void kernel_launch(void* const* d_in, const int* in_sizes, int n_in,
                              void* d_out, int out_size, void* d_ws, size_t ws_size,
                              hipStream_t stream) {
    const float* x    = (const float*)d_in[0];
    const int*   esrc = (const int*)d_in[1];
    const int*   edst = (const int*)d_in[2];
    const float* ew   = (const float*)d_in[3];
    const float* W1   = (const float*)d_in[4];
    const float* b1   = (const float*)d_in[5];
    const float* W2   = (const float*)d_in[6];
    const float* b2   = (const float*)d_in[7];
    float* out = (float*)d_out;

    char* ws = (char*)d_ws;
    size_t off = 0;
    auto alloc = [&](size_t bytes) {
        size_t o = off;
        off = (off + bytes + 255) & ~(size_t)255;
        return o;
    };
    __hip_bfloat16* support0 = (__hip_bfloat16*)(ws + alloc((size_t)N_NODES * NHID * 2));
    __hip_bfloat16* H0       = (__hip_bfloat16*)(ws + alloc((size_t)N_NODES * NHID * 2));
    __hip_bfloat16* support1 = (__hip_bfloat16*)(ws + alloc((size_t)N_NODES * NCLASS * 2));
    int*   src_sorted = (int*)(ws + alloc((size_t)N_EDGES * 4));
    float* w_sorted   = (float*)(ws + alloc((size_t)N_EDGES * 4));
    int*   row_ptr    = (int*)(ws + alloc((size_t)(N_NODES + 1) * 4));
    int*   cursor     = (int*)(ws + alloc((size_t)N_NODES * 4));
    int*   partials   = (int*)(ws + alloc(256 * 4));
    __hip_bfloat16* W1T = (__hip_bfloat16*)(ws + alloc((size_t)NHID * NFEAT * 2));
    __hip_bfloat16* W2T = (__hip_bfloat16*)(ws + alloc((size_t)NCLASS * NHID * 2));

    // --- weight transposes (bf16) ---
    transpose_w_kernel<<<(NFEAT * NHID + 255) / 256, 256, 0, stream>>>(W1, W1T, NFEAT, NHID);
    transpose_w_kernel<<<(NHID * NCLASS + 255) / 256, 256, 0, stream>>>(W2, W2T, NHID, NCLASS);

    // --- CSR build ---
    hipMemsetAsync(cursor, 0, (size_t)N_NODES * 4, stream);
    hist_kernel<<<2048, 256, 0, stream>>>(edst, cursor);
    scan_part_kernel<<<NB, 256, 0, stream>>>(cursor, partials);
    scan_mid_kernel<<<1, 64, 0, stream>>>(partials);
    scan_final_kernel<<<NB, 256, 0, stream>>>(cursor, row_ptr, partials);
    scatter_kernel<<<2048, 256, 0, stream>>>(esrc, edst, ew, cursor, src_sorted, w_sorted);

    // --- Layer 1 ---
    gemm1_mfma<<<dim3((N_NODES + 127) / 128, NHID / 128), 256, 0, stream>>>(x, W1T, support0, N_NODES);
    spmm1_kernel<<<N_NODES, 256, 0, stream>>>(support0, row_ptr, src_sorted, w_sorted, b1, H0);

    // --- Layer 2 ---
    gemm2_mfma<<<(N_NODES + 127) / 128, 256, 0, stream>>>(H0, W2T, support1, N_NODES);
    spmm2_softmax_kernel<<<N_NODES / 4, 256, 0, stream>>>(support1, row_ptr, src_sorted,
                                                          w_sorted, b2, out);
}

// Round 3
// 845.028 us; speedup vs baseline: 1.9791x; 1.2195x over previous
//
#include <hip/hip_runtime.h>
#include <hip/hip_bf16.h>

// ---------------- problem constants (match reference) ----------------
static constexpr int N_NODES = 100000;
static constexpr int N_EDGES = 3200000;
static constexpr int NFEAT   = 512;
static constexpr int NHID    = 256;
static constexpr int NCLASS  = 64;

static constexpr int SCAN_CHUNK = 2048;                       // 256 thr * 8 items
static constexpr int NB = (N_NODES + SCAN_CHUNK - 1) / SCAN_CHUNK; // 49

using short8 = __attribute__((ext_vector_type(8))) short;
using f32x4  = __attribute__((ext_vector_type(4))) float;
using fv4    = __attribute__((ext_vector_type(4))) float;

__device__ __forceinline__ float to_f32(float v) { return v; }
__device__ __forceinline__ float to_f32(__hip_bfloat16 v) { return __bfloat162float(v); }

__device__ __forceinline__ short f2bf_bits(float f) {
    __hip_bfloat16 h = __float2bfloat16(f);
    return *reinterpret_cast<short*>(&h);
}

__device__ __forceinline__ float bfbits2f(short b) {
    unsigned u = ((unsigned)(unsigned short)b) << 16;
    return __int_as_float(u);
}

#define GLOBAL_TO_LDS(gsrc, ldst)                                                        \
    __builtin_amdgcn_global_load_lds((const __attribute__((address_space(1))) void*)(gsrc), \
                                     (__attribute__((address_space(3))) void*)(ldst), 16, 0, 0)

// ---------------- CSR build ----------------
__global__ __launch_bounds__(256) void hist_kernel(const int4* __restrict__ edst4,
                                                   int* __restrict__ counts) {
    int i = blockIdx.x * 256 + threadIdx.x;
    if (i < N_EDGES / 4) {
        int4 v = edst4[i];
        atomicAdd(&counts[v.x], 1);
        atomicAdd(&counts[v.y], 1);
        atomicAdd(&counts[v.z], 1);
        atomicAdd(&counts[v.w], 1);
    }
}

__global__ __launch_bounds__(256) void scan_part_kernel(const int* __restrict__ counts,
                                                        int* __restrict__ partials) {
    int b = blockIdx.x, t = threadIdx.x;
    int base = b * SCAN_CHUNK + t * 8;
    int s = 0;
#pragma unroll
    for (int j = 0; j < 8; ++j) {
        int i = base + j;
        if (i < N_NODES) s += counts[i];
    }
    __shared__ int sd[256];
    sd[t] = s;
    __syncthreads();
    for (int off = 128; off > 0; off >>= 1) {
        if (t < off) sd[t] += sd[t + off];
        __syncthreads();
    }
    if (t == 0) partials[b] = sd[0];
}

__global__ void scan_mid_kernel(int* __restrict__ partials) {
    if (threadIdx.x == 0) {
        int run = 0;
        for (int i = 0; i < NB; ++i) {
            int v = partials[i];
            partials[i] = run;
            run += v;
        }
    }
}

__global__ __launch_bounds__(256) void scan_final_kernel(int* __restrict__ counts_cursor,
                                                         int* __restrict__ row_ptr,
                                                         const int* __restrict__ partials) {
    int b = blockIdx.x, t = threadIdx.x;
    int base = b * SCAN_CHUNK + t * 8;
    int v[8];
    int tsum = 0;
#pragma unroll
    for (int j = 0; j < 8; ++j) {
        int i = base + j;
        v[j] = (i < N_NODES) ? counts_cursor[i] : 0;
        tsum += v[j];
    }
    __shared__ int sd[256];
    sd[t] = tsum;
    __syncthreads();
    for (int off = 1; off < 256; off <<= 1) {
        int x = (t >= off) ? sd[t - off] : 0;
        __syncthreads();
        sd[t] += x;
        __syncthreads();
    }
    int run = sd[t] - tsum + partials[b];
#pragma unroll
    for (int j = 0; j < 8; ++j) {
        int i = base + j;
        if (i < N_NODES) {
            row_ptr[i] = run;
            counts_cursor[i] = run;
        }
        run += v[j];
    }
    if (b == 0 && t == 0) row_ptr[N_NODES] = N_EDGES;
}

// packed scatter: one 8B store per edge (src, w-bits)
__global__ __launch_bounds__(256) void scatter_kernel(const int* __restrict__ esrc,
                                                      const int* __restrict__ edst,
                                                      const float* __restrict__ ew,
                                                      int* __restrict__ cursor,
                                                      int2* __restrict__ pk) {
    int e = blockIdx.x * 256 + threadIdx.x;
    if (e < N_EDGES) {
        int d = edst[e];
        int pos = atomicAdd(&cursor[d], 1);
        pk[pos] = make_int2(esrc[e], __float_as_int(ew[e]));
    }
}

// ---------------- small transpose+cast: W[K][N] f32 -> WT[N][K] bf16 ----------------
__global__ __launch_bounds__(256) void transpose_w_kernel(const float* __restrict__ W,
                                                          __hip_bfloat16* __restrict__ WT,
                                                          int K, int N) {
    int idx = blockIdx.x * 256 + threadIdx.x;
    if (idx < K * N) {
        int k = idx / N, n = idx % N;
        WT[(size_t)n * K + k] = __float2bfloat16(W[idx]);
    }
}

// ---------------- GEMM1: C[M,256] = A[M,512](f32) @ W1T[256,512](bf16)^T, C bf16 ----
__global__ __launch_bounds__(256) void gemm1_mfma(const float* __restrict__ A,
                                                  const __hip_bfloat16* __restrict__ BT,
                                                  __hip_bfloat16* __restrict__ C,
                                                  int M) {
    constexpr int K = NFEAT;   // 512
    constexpr int N = NHID;    // 256
    constexpr int BM = 128, BN = 128, BK = 32;
    __shared__ __align__(16) __hip_bfloat16 Bs[BN * BK];  // 8 KB
    const int tid = threadIdx.x;
    const int lane = tid & 63, wave = tid >> 6;
    const int wr = wave >> 1, wc = wave & 1;
    const int laneRow = lane & 15, laneK = lane >> 4;
    const int row0 = blockIdx.x * BM, col0 = blockIdx.y * BN;

    f32x4 acc[4][4] = {};

    int arow[4];
#pragma unroll
    for (int i = 0; i < 4; ++i) {
        int r = row0 + wr * 64 + i * 16 + laneRow;
        arow[i] = (r < M) ? r : (M - 1);
    }

    for (int k0 = 0; k0 < K; k0 += BK) {
#pragma unroll
        for (int it = 0; it < 2; ++it) {
            int idx = tid + it * 256;
            int n = idx >> 2;
            int gk = (idx & 3) ^ ((n >> 1) & 3);
            const __hip_bfloat16* src = BT + (size_t)(col0 + n) * K + k0 + gk * 8;
            GLOBAL_TO_LDS(src, Bs + (size_t)idx * 8);
        }
        short8 af[4];
#pragma unroll
        for (int i = 0; i < 4; ++i) {
            const float* ap = A + (size_t)arow[i] * K + k0 + laneK * 8;
            fv4 a0 = *(const fv4*)ap;
            fv4 a1 = *(const fv4*)(ap + 4);
            short8 v;
#pragma unroll
            for (int j = 0; j < 4; ++j) v[j] = f2bf_bits(a0[j]);
#pragma unroll
            for (int j = 0; j < 4; ++j) v[4 + j] = f2bf_bits(a1[j]);
            af[i] = v;
        }
        __syncthreads();
        short8 bfr[4];
#pragma unroll
        for (int j = 0; j < 4; ++j) {
            int n = wc * 64 + j * 16 + laneRow;
            int pg = laneK ^ ((n >> 1) & 3);
            bfr[j] = *(const short8*)(Bs + n * BK + pg * 8);
        }
#pragma unroll
        for (int i = 0; i < 4; ++i)
#pragma unroll
            for (int j = 0; j < 4; ++j)
                acc[i][j] = __builtin_amdgcn_mfma_f32_16x16x32_bf16(af[i], bfr[j], acc[i][j], 0, 0, 0);
        __syncthreads();
    }
#pragma unroll
    for (int i = 0; i < 4; ++i) {
        int rbase = row0 + wr * 64 + i * 16 + laneK * 4;
#pragma unroll
        for (int j = 0; j < 4; ++j) {
            int col = col0 + wc * 64 + j * 16 + laneRow;
#pragma unroll
            for (int q = 0; q < 4; ++q) {
                int row = rbase + q;
                if (row < M) C[(size_t)row * N + col] = __float2bfloat16(acc[i][j][q]);
            }
        }
    }
}

// ---------------- GEMM2: C[M,64] = A[M,256](bf16) @ W2T[64,256](bf16)^T, C bf16 ----
__global__ __launch_bounds__(256) void gemm2_mfma(const __hip_bfloat16* __restrict__ A,
                                                  const __hip_bfloat16* __restrict__ BT,
                                                  __hip_bfloat16* __restrict__ C,
                                                  int M) {
    constexpr int K = NHID;    // 256
    constexpr int N = NCLASS;  // 64
    constexpr int BM = 128;
    __shared__ __align__(16) __hip_bfloat16 Bs[N * K];  // 32 KB
    const int tid = threadIdx.x;
    const int lane = tid & 63, wave = tid >> 6;
    const int wr = wave >> 1, wc = wave & 1;
    const int laneRow = lane & 15, laneK = lane >> 4;
    const int row0 = blockIdx.x * BM;

#pragma unroll
    for (int it = 0; it < 8; ++it) {
        int idx = tid + it * 256;
        int n = idx >> 5;
        int kk = (idx & 31) ^ (n & 7);
        const __hip_bfloat16* src = BT + (size_t)n * K + kk * 8;
        GLOBAL_TO_LDS(src, Bs + (size_t)idx * 8);
    }

    int arow[4];
#pragma unroll
    for (int i = 0; i < 4; ++i) {
        int r = row0 + wr * 64 + i * 16 + laneRow;
        arow[i] = (r < M) ? r : (M - 1);
    }

    f32x4 acc[4][2] = {};
    __syncthreads();

#pragma unroll
    for (int k0 = 0; k0 < K; k0 += 32) {
        short8 af[4];
#pragma unroll
        for (int i = 0; i < 4; ++i)
            af[i] = *(const short8*)(A + (size_t)arow[i] * K + k0 + laneK * 8);
        short8 bfr[2];
#pragma unroll
        for (int j = 0; j < 2; ++j) {
            int n = wc * 32 + j * 16 + laneRow;
            int kkw = (k0 >> 3) + laneK;
            int pkk = kkw ^ (n & 7);
            bfr[j] = *(const short8*)(Bs + (size_t)n * 32 * 8 + pkk * 8);
        }
#pragma unroll
        for (int i = 0; i < 4; ++i)
#pragma unroll
            for (int j = 0; j < 2; ++j)
                acc[i][j] = __builtin_amdgcn_mfma_f32_16x16x32_bf16(af[i], bfr[j], acc[i][j], 0, 0, 0);
    }

#pragma unroll
    for (int i = 0; i < 4; ++i) {
        int rbase = row0 + wr * 64 + i * 16 + laneK * 4;
#pragma unroll
        for (int j = 0; j < 2; ++j) {
            int col = wc * 32 + j * 16 + laneRow;
#pragma unroll
            for (int q = 0; q < 4; ++q) {
                int row = rbase + q;
                if (row < M) C[(size_t)row * N + col] = __float2bfloat16(acc[i][j][q]);
            }
        }
    }
}

// ---------------- SPMM layer1 (one node per wave, 2 edge slots x 32 chunks) ----------
// H0[d, c*8+k] = relu( sum_e w_e * support0[src_e, c*8+k] + b1 )
__global__ __launch_bounds__(256) void spmm1_kernel(const __hip_bfloat16* __restrict__ support0,
                                                    const int* __restrict__ row_ptr,
                                                    const int2* __restrict__ pk,
                                                    const float* __restrict__ b1,
                                                    __hip_bfloat16* __restrict__ H0) {
    int node = blockIdx.x * 4 + (threadIdx.x >> 6);
    int lane = threadIdx.x & 63;
    int j = lane >> 5;   // edge slot 0..1
    int c = lane & 31;   // column chunk (8 cols each)
    int beg = row_ptr[node], end = row_ptr[node + 1];
    float acc[8] = {};
    for (int base = beg; base + j < end; base += 2) {
        int2 pe = pk[base + j];
        float w = __int_as_float(pe.y);
        short8 v = *(const short8*)(support0 + (size_t)pe.x * NHID + c * 8);
#pragma unroll
        for (int k = 0; k < 8; ++k) acc[k] += w * bfbits2f(v[k]);
    }
#pragma unroll
    for (int k = 0; k < 8; ++k) acc[k] += __shfl_xor(acc[k], 32);
    if (lane < 32) {
        fv4 blo = *(const fv4*)(b1 + c * 8);
        fv4 bhi = *(const fv4*)(b1 + c * 8 + 4);
        short8 o;
#pragma unroll
        for (int k = 0; k < 4; ++k) o[k] = f2bf_bits(fmaxf(acc[k] + blo[k], 0.f));
#pragma unroll
        for (int k = 0; k < 4; ++k) o[4 + k] = f2bf_bits(fmaxf(acc[4 + k] + bhi[k], 0.f));
        *(short8*)(H0 + (size_t)node * NHID + c * 8) = o;
    }
}

// ---------------- SPMM layer2 + bias + log_softmax (one node per wave, 8x8) ---------
__global__ __launch_bounds__(256) void spmm2_softmax_kernel(const __hip_bfloat16* __restrict__ support1,
                                                            const int* __restrict__ row_ptr,
                                                            const int2* __restrict__ pk,
                                                            const float* __restrict__ b2,
                                                            float* __restrict__ out) {
    int node = blockIdx.x * 4 + (threadIdx.x >> 6);
    int lane = threadIdx.x & 63;
    int j = lane >> 3;   // edge slot 0..7
    int c = lane & 7;    // class chunk (8 classes each)
    int beg = row_ptr[node], end = row_ptr[node + 1];
    float acc[8] = {};
    for (int base = beg; base + j < end; base += 8) {
        int2 pe = pk[base + j];
        float w = __int_as_float(pe.y);
        short8 v = *(const short8*)(support1 + (size_t)pe.x * NCLASS + c * 8);
#pragma unroll
        for (int k = 0; k < 8; ++k) acc[k] += w * bfbits2f(v[k]);
    }
    // fold edge slots (lanes differing in bits 3..5 share the same chunk c)
#pragma unroll
    for (int m = 8; m < 64; m <<= 1)
#pragma unroll
        for (int k = 0; k < 8; ++k) acc[k] += __shfl_xor(acc[k], m);

    fv4 blo = *(const fv4*)(b2 + c * 8);
    fv4 bhi = *(const fv4*)(b2 + c * 8 + 4);
    float z[8];
#pragma unroll
    for (int k = 0; k < 4; ++k) z[k] = acc[k] + blo[k];
#pragma unroll
    for (int k = 0; k < 4; ++k) z[4 + k] = acc[4 + k] + bhi[k];

    float mx = z[0];
#pragma unroll
    for (int k = 1; k < 8; ++k) mx = fmaxf(mx, z[k]);
#pragma unroll
    for (int m = 1; m < 8; m <<= 1) mx = fmaxf(mx, __shfl_xor(mx, m));
    float s = 0.f;
#pragma unroll
    for (int k = 0; k < 8; ++k) s += __expf(z[k] - mx);
#pragma unroll
    for (int m = 1; m < 8; m <<= 1) s += __shfl_xor(s, m);
    float lg = __logf(s);
    if (lane < 8) {
        f32x4 o0, o1;
#pragma unroll
        for (int k = 0; k < 4; ++k) o0[k] = z[k] - mx - lg;
#pragma unroll
        for (int k = 0; k < 4; ++k) o1[k] = z[4 + k] - mx - lg;
        float* dst = out + (size_t)node * NCLASS + c * 8;
        *(f32x4*)dst = o0;
        *(f32x4*)(dst + 4) = o1;
    }
}

// ---------------- host launch ----------------
extern "C" void kernel_launch(void* const* d_in, const int* in_sizes, int n_in,
                              void* d_out, int out_size, void* d_ws, size_t ws_size,
                              hipStream_t stream) {
    const float* x    = (const float*)d_in[0];
    const int*   esrc = (const int*)d_in[1];
    const int*   edst = (const int*)d_in[2];
    const float* ew   = (const float*)d_in[3];
    const float* W1   = (const float*)d_in[4];
    const float* b1   = (const float*)d_in[5];
    const float* W2   = (const float*)d_in[6];
    const float* b2   = (const float*)d_in[7];
    float* out = (float*)d_out;

    char* ws = (char*)d_ws;
    size_t off = 0;
    auto alloc = [&](size_t bytes) {
        size_t o = off;
        off = (off + bytes + 255) & ~(size_t)255;
        return o;
    };
    __hip_bfloat16* support0 = (__hip_bfloat16*)(ws + alloc((size_t)N_NODES * NHID * 2));
    __hip_bfloat16* H0       = (__hip_bfloat16*)(ws + alloc((size_t)N_NODES * NHID * 2));
    __hip_bfloat16* support1 = (__hip_bfloat16*)(ws + alloc((size_t)N_NODES * NCLASS * 2));
    int2*  pk         = (int2*)(ws + alloc((size_t)N_EDGES * 8));
    int*   row_ptr    = (int*)(ws + alloc((size_t)(N_NODES + 1) * 4));
    int*   cursor     = (int*)(ws + alloc((size_t)N_NODES * 4));
    int*   partials   = (int*)(ws + alloc(256 * 4));
    __hip_bfloat16* W1T = (__hip_bfloat16*)(ws + alloc((size_t)NHID * NFEAT * 2));
    __hip_bfloat16* W2T = (__hip_bfloat16*)(ws + alloc((size_t)NCLASS * NHID * 2));

    // --- weight transposes (bf16) ---
    transpose_w_kernel<<<(NFEAT * NHID + 255) / 256, 256, 0, stream>>>(W1, W1T, NFEAT, NHID);
    transpose_w_kernel<<<(NHID * NCLASS + 255) / 256, 256, 0, stream>>>(W2, W2T, NHID, NCLASS);

    // --- CSR build ---
    hipMemsetAsync(cursor, 0, (size_t)N_NODES * 4, stream);
    hist_kernel<<<(N_EDGES / 4 + 255) / 256, 256, 0, stream>>>((const int4*)edst, cursor);
    scan_part_kernel<<<NB, 256, 0, stream>>>(cursor, partials);
    scan_mid_kernel<<<1, 64, 0, stream>>>(partials);
    scan_final_kernel<<<NB, 256, 0, stream>>>(cursor, row_ptr, partials);
    scatter_kernel<<<(N_EDGES + 255) / 256, 256, 0, stream>>>(esrc, edst, ew, cursor, pk);

    // --- Layer 1 ---
    gemm1_mfma<<<dim3((N_NODES + 127) / 128, NHID / 128), 256, 0, stream>>>(x, W1T, support0, N_NODES);
    spmm1_kernel<<<N_NODES / 4, 256, 0, stream>>>(support0, row_ptr, pk, b1, H0);

    // --- Layer 2 ---
    gemm2_mfma<<<(N_NODES + 127) / 128, 256, 0, stream>>>(H0, W2T, support1, N_NODES);
    spmm2_softmax_kernel<<<N_NODES / 4, 256, 0, stream>>>(support1, row_ptr, pk, b2, out);
}

// Round 4
// 760.736 us; speedup vs baseline: 2.1984x; 1.1108x over previous
//
#include <hip/hip_runtime.h>
#include <hip/hip_bf16.h>

// ---------------- problem constants (match reference) ----------------
static constexpr int N_NODES = 100000;
static constexpr int N_EDGES = 3200000;
static constexpr int NFEAT   = 512;
static constexpr int NHID    = 256;
static constexpr int NCLASS  = 64;

static constexpr int SCAN_CHUNK = 2048;                       // 256 thr * 8 items
static constexpr int NB = (N_NODES + SCAN_CHUNK - 1) / SCAN_CHUNK; // 49

// dst-partitioned CSR build (XCD-local writes/atomics)
static constexpr int PARTS = 8;
static constexpr int NODES_PER_PART = N_NODES / PARTS;         // 12500
static constexpr int EDGES_PER_BLOCK = 1024;                   // 256 thr * 4
static constexpr int NCHUNK = N_EDGES / EDGES_PER_BLOCK;       // 3125

using short8 = __attribute__((ext_vector_type(8))) short;
using f32x4  = __attribute__((ext_vector_type(4))) float;
using fv4    = __attribute__((ext_vector_type(4))) float;

__device__ __forceinline__ float to_f32(float v) { return v; }
__device__ __forceinline__ float to_f32(__hip_bfloat16 v) { return __bfloat162float(v); }

__device__ __forceinline__ short f2bf_bits(float f) {
    __hip_bfloat16 h = __float2bfloat16(f);
    return *reinterpret_cast<short*>(&h);
}

__device__ __forceinline__ float bfbits2f(short b) {
    unsigned u = ((unsigned)(unsigned short)b) << 16;
    return __int_as_float(u);
}

#define GLOBAL_TO_LDS(gsrc, ldst)                                                        \
    __builtin_amdgcn_global_load_lds((const __attribute__((address_space(1))) void*)(gsrc), \
                                     (__attribute__((address_space(3))) void*)(ldst), 16, 0, 0)

// ---------------- CSR build (dst-partitioned) ----------------
__global__ __launch_bounds__(256) void hist_part_kernel(const int* __restrict__ edst,
                                                        int* __restrict__ counts) {
    int p = blockIdx.x & (PARTS - 1);
    int chunk = blockIdx.x >> 3;
    int e0 = chunk * EDGES_PER_BLOCK + threadIdx.x * 4;
    int lo = p * NODES_PER_PART, hi = lo + NODES_PER_PART;
    int4 d4 = *(const int4*)(edst + e0);
    int dd[4] = {d4.x, d4.y, d4.z, d4.w};
#pragma unroll
    for (int k = 0; k < 4; ++k)
        if (dd[k] >= lo && dd[k] < hi) atomicAdd(&counts[dd[k]], 1);
}

__global__ __launch_bounds__(256) void scan_part_kernel(const int* __restrict__ counts,
                                                        int* __restrict__ partials) {
    int b = blockIdx.x, t = threadIdx.x;
    int base = b * SCAN_CHUNK + t * 8;
    int s = 0;
#pragma unroll
    for (int j = 0; j < 8; ++j) {
        int i = base + j;
        if (i < N_NODES) s += counts[i];
    }
    __shared__ int sd[256];
    sd[t] = s;
    __syncthreads();
    for (int off = 128; off > 0; off >>= 1) {
        if (t < off) sd[t] += sd[t + off];
        __syncthreads();
    }
    if (t == 0) partials[b] = sd[0];
}

__global__ void scan_mid_kernel(int* __restrict__ partials) {
    if (threadIdx.x == 0) {
        int run = 0;
        for (int i = 0; i < NB; ++i) {
            int v = partials[i];
            partials[i] = run;
            run += v;
        }
    }
}

__global__ __launch_bounds__(256) void scan_final_kernel(int* __restrict__ counts_cursor,
                                                         int* __restrict__ row_ptr,
                                                         const int* __restrict__ partials) {
    int b = blockIdx.x, t = threadIdx.x;
    int base = b * SCAN_CHUNK + t * 8;
    int v[8];
    int tsum = 0;
#pragma unroll
    for (int j = 0; j < 8; ++j) {
        int i = base + j;
        v[j] = (i < N_NODES) ? counts_cursor[i] : 0;
        tsum += v[j];
    }
    __shared__ int sd[256];
    sd[t] = tsum;
    __syncthreads();
    for (int off = 1; off < 256; off <<= 1) {
        int x = (t >= off) ? sd[t - off] : 0;
        __syncthreads();
        sd[t] += x;
        __syncthreads();
    }
    int run = sd[t] - tsum + partials[b];
#pragma unroll
    for (int j = 0; j < 8; ++j) {
        int i = base + j;
        if (i < N_NODES) {
            row_ptr[i] = run;
            counts_cursor[i] = run;
        }
        run += v[j];
    }
    if (b == 0 && t == 0) row_ptr[N_NODES] = N_EDGES;
}

// partitioned packed scatter: block (chunk, p) stores only edges with dst in partition p.
// Partition p's pk region (~3.2 MB) + cursors stay resident in one XCD's L2.
__global__ __launch_bounds__(256) void scatter_part_kernel(const int* __restrict__ esrc,
                                                           const int* __restrict__ edst,
                                                           const float* __restrict__ ew,
                                                           int* __restrict__ cursor,
                                                           int2* __restrict__ pk) {
    int p = blockIdx.x & (PARTS - 1);
    int chunk = blockIdx.x >> 3;
    int e0 = chunk * EDGES_PER_BLOCK + threadIdx.x * 4;
    int lo = p * NODES_PER_PART, hi = lo + NODES_PER_PART;
    int4 d4 = *(const int4*)(edst + e0);
    int4 s4 = *(const int4*)(esrc + e0);
    float4 w4 = *(const float4*)(ew + e0);
    int   dd[4] = {d4.x, d4.y, d4.z, d4.w};
    int   ss[4] = {s4.x, s4.y, s4.z, s4.w};
    float ww[4] = {w4.x, w4.y, w4.z, w4.w};
#pragma unroll
    for (int k = 0; k < 4; ++k) {
        if (dd[k] >= lo && dd[k] < hi) {
            int pos = atomicAdd(&cursor[dd[k]], 1);
            pk[pos] = make_int2(ss[k], __float_as_int(ww[k]));
        }
    }
}

// ---------------- small transpose+cast: W[K][N] f32 -> WT[N][K] bf16 ----------------
__global__ __launch_bounds__(256) void transpose_w_kernel(const float* __restrict__ W,
                                                          __hip_bfloat16* __restrict__ WT,
                                                          int K, int N) {
    int idx = blockIdx.x * 256 + threadIdx.x;
    if (idx < K * N) {
        int k = idx / N, n = idx % N;
        WT[(size_t)n * K + k] = __float2bfloat16(W[idx]);
    }
}

// ---------------- GEMM1: C[M,256] = A[M,512](f32) @ W1T[256,512](bf16)^T, C bf16 ----
__global__ __launch_bounds__(256) void gemm1_mfma(const float* __restrict__ A,
                                                  const __hip_bfloat16* __restrict__ BT,
                                                  __hip_bfloat16* __restrict__ C,
                                                  int M) {
    constexpr int K = NFEAT;   // 512
    constexpr int N = NHID;    // 256
    constexpr int BM = 128, BN = 128, BK = 32;
    __shared__ __align__(16) __hip_bfloat16 Bs[BN * BK];  // 8 KB
    const int tid = threadIdx.x;
    const int lane = tid & 63, wave = tid >> 6;
    const int wr = wave >> 1, wc = wave & 1;
    const int laneRow = lane & 15, laneK = lane >> 4;
    const int row0 = blockIdx.x * BM, col0 = blockIdx.y * BN;

    f32x4 acc[4][4] = {};

    int arow[4];
#pragma unroll
    for (int i = 0; i < 4; ++i) {
        int r = row0 + wr * 64 + i * 16 + laneRow;
        arow[i] = (r < M) ? r : (M - 1);
    }

    for (int k0 = 0; k0 < K; k0 += BK) {
#pragma unroll
        for (int it = 0; it < 2; ++it) {
            int idx = tid + it * 256;
            int n = idx >> 2;
            int gk = (idx & 3) ^ ((n >> 1) & 3);
            const __hip_bfloat16* src = BT + (size_t)(col0 + n) * K + k0 + gk * 8;
            GLOBAL_TO_LDS(src, Bs + (size_t)idx * 8);
        }
        short8 af[4];
#pragma unroll
        for (int i = 0; i < 4; ++i) {
            const float* ap = A + (size_t)arow[i] * K + k0 + laneK * 8;
            fv4 a0 = *(const fv4*)ap;
            fv4 a1 = *(const fv4*)(ap + 4);
            short8 v;
#pragma unroll
            for (int j = 0; j < 4; ++j) v[j] = f2bf_bits(a0[j]);
#pragma unroll
            for (int j = 0; j < 4; ++j) v[4 + j] = f2bf_bits(a1[j]);
            af[i] = v;
        }
        __syncthreads();
        short8 bfr[4];
#pragma unroll
        for (int j = 0; j < 4; ++j) {
            int n = wc * 64 + j * 16 + laneRow;
            int pg = laneK ^ ((n >> 1) & 3);
            bfr[j] = *(const short8*)(Bs + n * BK + pg * 8);
        }
#pragma unroll
        for (int i = 0; i < 4; ++i)
#pragma unroll
            for (int j = 0; j < 4; ++j)
                acc[i][j] = __builtin_amdgcn_mfma_f32_16x16x32_bf16(af[i], bfr[j], acc[i][j], 0, 0, 0);
        __syncthreads();
    }
#pragma unroll
    for (int i = 0; i < 4; ++i) {
        int rbase = row0 + wr * 64 + i * 16 + laneK * 4;
#pragma unroll
        for (int j = 0; j < 4; ++j) {
            int col = col0 + wc * 64 + j * 16 + laneRow;
#pragma unroll
            for (int q = 0; q < 4; ++q) {
                int row = rbase + q;
                if (row < M) C[(size_t)row * N + col] = __float2bfloat16(acc[i][j][q]);
            }
        }
    }
}

// ---------------- GEMM2: C[M,64] = A[M,256](bf16) @ W2T[64,256](bf16)^T, C bf16 ----
__global__ __launch_bounds__(256) void gemm2_mfma(const __hip_bfloat16* __restrict__ A,
                                                  const __hip_bfloat16* __restrict__ BT,
                                                  __hip_bfloat16* __restrict__ C,
                                                  int M) {
    constexpr int K = NHID;    // 256
    constexpr int N = NCLASS;  // 64
    constexpr int BM = 128;
    __shared__ __align__(16) __hip_bfloat16 Bs[N * K];  // 32 KB
    const int tid = threadIdx.x;
    const int lane = tid & 63, wave = tid >> 6;
    const int wr = wave >> 1, wc = wave & 1;
    const int laneRow = lane & 15, laneK = lane >> 4;
    const int row0 = blockIdx.x * BM;

#pragma unroll
    for (int it = 0; it < 8; ++it) {
        int idx = tid + it * 256;
        int n = idx >> 5;
        int kk = (idx & 31) ^ (n & 7);
        const __hip_bfloat16* src = BT + (size_t)n * K + kk * 8;
        GLOBAL_TO_LDS(src, Bs + (size_t)idx * 8);
    }

    int arow[4];
#pragma unroll
    for (int i = 0; i < 4; ++i) {
        int r = row0 + wr * 64 + i * 16 + laneRow;
        arow[i] = (r < M) ? r : (M - 1);
    }

    f32x4 acc[4][2] = {};
    __syncthreads();

#pragma unroll
    for (int k0 = 0; k0 < K; k0 += 32) {
        short8 af[4];
#pragma unroll
        for (int i = 0; i < 4; ++i)
            af[i] = *(const short8*)(A + (size_t)arow[i] * K + k0 + laneK * 8);
        short8 bfr[2];
#pragma unroll
        for (int j = 0; j < 2; ++j) {
            int n = wc * 32 + j * 16 + laneRow;
            int kkw = (k0 >> 3) + laneK;
            int pkk = kkw ^ (n & 7);
            bfr[j] = *(const short8*)(Bs + (size_t)n * 32 * 8 + pkk * 8);
        }
#pragma unroll
        for (int i = 0; i < 4; ++i)
#pragma unroll
            for (int j = 0; j < 2; ++j)
                acc[i][j] = __builtin_amdgcn_mfma_f32_16x16x32_bf16(af[i], bfr[j], acc[i][j], 0, 0, 0);
    }

#pragma unroll
    for (int i = 0; i < 4; ++i) {
        int rbase = row0 + wr * 64 + i * 16 + laneK * 4;
#pragma unroll
        for (int j = 0; j < 2; ++j) {
            int col = wc * 32 + j * 16 + laneRow;
#pragma unroll
            for (int q = 0; q < 4; ++q) {
                int row = rbase + q;
                if (row < M) C[(size_t)row * N + col] = __float2bfloat16(acc[i][j][q]);
            }
        }
    }
}

// ---------------- SPMM layer1 (one node per wave, 2 edge slots x 32 chunks) ----------
__global__ __launch_bounds__(256) void spmm1_kernel(const __hip_bfloat16* __restrict__ support0,
                                                    const int* __restrict__ row_ptr,
                                                    const int2* __restrict__ pk,
                                                    const float* __restrict__ b1,
                                                    __hip_bfloat16* __restrict__ H0) {
    int node = blockIdx.x * 4 + (threadIdx.x >> 6);
    int lane = threadIdx.x & 63;
    int j = lane >> 5;   // edge slot 0..1
    int c = lane & 31;   // column chunk (8 cols each)
    int beg = row_ptr[node], end = row_ptr[node + 1];
    float acc[8] = {};
    for (int base = beg; base + j < end; base += 2) {
        int2 pe = pk[base + j];
        float w = __int_as_float(pe.y);
        short8 v = *(const short8*)(support0 + (size_t)pe.x * NHID + c * 8);
#pragma unroll
        for (int k = 0; k < 8; ++k) acc[k] += w * bfbits2f(v[k]);
    }
#pragma unroll
    for (int k = 0; k < 8; ++k) acc[k] += __shfl_xor(acc[k], 32);
    if (lane < 32) {
        fv4 blo = *(const fv4*)(b1 + c * 8);
        fv4 bhi = *(const fv4*)(b1 + c * 8 + 4);
        short8 o;
#pragma unroll
        for (int k = 0; k < 4; ++k) o[k] = f2bf_bits(fmaxf(acc[k] + blo[k], 0.f));
#pragma unroll
        for (int k = 0; k < 4; ++k) o[4 + k] = f2bf_bits(fmaxf(acc[4 + k] + bhi[k], 0.f));
        *(short8*)(H0 + (size_t)node * NHID + c * 8) = o;
    }
}

// ---------------- SPMM layer2 + bias + log_softmax (one node per wave, 8x8) ---------
__global__ __launch_bounds__(256) void spmm2_softmax_kernel(const __hip_bfloat16* __restrict__ support1,
                                                            const int* __restrict__ row_ptr,
                                                            const int2* __restrict__ pk,
                                                            const float* __restrict__ b2,
                                                            float* __restrict__ out) {
    int node = blockIdx.x * 4 + (threadIdx.x >> 6);
    int lane = threadIdx.x & 63;
    int j = lane >> 3;   // edge slot 0..7
    int c = lane & 7;    // class chunk (8 classes each)
    int beg = row_ptr[node], end = row_ptr[node + 1];
    float acc[8] = {};
    for (int base = beg; base + j < end; base += 8) {
        int2 pe = pk[base + j];
        float w = __int_as_float(pe.y);
        short8 v = *(const short8*)(support1 + (size_t)pe.x * NCLASS + c * 8);
#pragma unroll
        for (int k = 0; k < 8; ++k) acc[k] += w * bfbits2f(v[k]);
    }
#pragma unroll
    for (int m = 8; m < 64; m <<= 1)
#pragma unroll
        for (int k = 0; k < 8; ++k) acc[k] += __shfl_xor(acc[k], m);

    fv4 blo = *(const fv4*)(b2 + c * 8);
    fv4 bhi = *(const fv4*)(b2 + c * 8 + 4);
    float z[8];
#pragma unroll
    for (int k = 0; k < 4; ++k) z[k] = acc[k] + blo[k];
#pragma unroll
    for (int k = 0; k < 4; ++k) z[4 + k] = acc[4 + k] + bhi[k];

    float mx = z[0];
#pragma unroll
    for (int k = 1; k < 8; ++k) mx = fmaxf(mx, z[k]);
#pragma unroll
    for (int m = 1; m < 8; m <<= 1) mx = fmaxf(mx, __shfl_xor(mx, m));
    float s = 0.f;
#pragma unroll
    for (int k = 0; k < 8; ++k) s += __expf(z[k] - mx);
#pragma unroll
    for (int m = 1; m < 8; m <<= 1) s += __shfl_xor(s, m);
    float lg = __logf(s);
    if (lane < 8) {
        f32x4 o0, o1;
#pragma unroll
        for (int k = 0; k < 4; ++k) o0[k] = z[k] - mx - lg;
#pragma unroll
        for (int k = 0; k < 4; ++k) o1[k] = z[4 + k] - mx - lg;
        float* dst = out + (size_t)node * NCLASS + c * 8;
        *(f32x4*)dst = o0;
        *(f32x4*)(dst + 4) = o1;
    }
}

// ---------------- host launch ----------------
extern "C" void kernel_launch(void* const* d_in, const int* in_sizes, int n_in,
                              void* d_out, int out_size, void* d_ws, size_t ws_size,
                              hipStream_t stream) {
    const float* x    = (const float*)d_in[0];
    const int*   esrc = (const int*)d_in[1];
    const int*   edst = (const int*)d_in[2];
    const float* ew   = (const float*)d_in[3];
    const float* W1   = (const float*)d_in[4];
    const float* b1   = (const float*)d_in[5];
    const float* W2   = (const float*)d_in[6];
    const float* b2   = (const float*)d_in[7];
    float* out = (float*)d_out;

    char* ws = (char*)d_ws;
    size_t off = 0;
    auto alloc = [&](size_t bytes) {
        size_t o = off;
        off = (off + bytes + 255) & ~(size_t)255;
        return o;
    };
    __hip_bfloat16* support0 = (__hip_bfloat16*)(ws + alloc((size_t)N_NODES * NHID * 2));
    __hip_bfloat16* H0       = (__hip_bfloat16*)(ws + alloc((size_t)N_NODES * NHID * 2));
    __hip_bfloat16* support1 = (__hip_bfloat16*)(ws + alloc((size_t)N_NODES * NCLASS * 2));
    int2*  pk         = (int2*)(ws + alloc((size_t)N_EDGES * 8));
    int*   row_ptr    = (int*)(ws + alloc((size_t)(N_NODES + 1) * 4));
    int*   cursor     = (int*)(ws + alloc((size_t)N_NODES * 4));
    int*   partials   = (int*)(ws + alloc(256 * 4));
    __hip_bfloat16* W1T = (__hip_bfloat16*)(ws + alloc((size_t)NHID * NFEAT * 2));
    __hip_bfloat16* W2T = (__hip_bfloat16*)(ws + alloc((size_t)NCLASS * NHID * 2));

    // --- weight transposes (bf16) ---
    transpose_w_kernel<<<(NFEAT * NHID + 255) / 256, 256, 0, stream>>>(W1, W1T, NFEAT, NHID);
    transpose_w_kernel<<<(NHID * NCLASS + 255) / 256, 256, 0, stream>>>(W2, W2T, NHID, NCLASS);

    // --- CSR build (dst-partitioned: partition = blockIdx & 7 -> XCD-local L2) ---
    hipMemsetAsync(cursor, 0, (size_t)N_NODES * 4, stream);
    hist_part_kernel<<<NCHUNK * PARTS, 256, 0, stream>>>(edst, cursor);
    scan_part_kernel<<<NB, 256, 0, stream>>>(cursor, partials);
    scan_mid_kernel<<<1, 64, 0, stream>>>(partials);
    scan_final_kernel<<<NB, 256, 0, stream>>>(cursor, row_ptr, partials);
    scatter_part_kernel<<<NCHUNK * PARTS, 256, 0, stream>>>(esrc, edst, ew, cursor, pk);

    // --- Layer 1 ---
    gemm1_mfma<<<dim3((N_NODES + 127) / 128, NHID / 128), 256, 0, stream>>>(x, W1T, support0, N_NODES);
    spmm1_kernel<<<N_NODES / 4, 256, 0, stream>>>(support0, row_ptr, pk, b1, H0);

    // --- Layer 2 ---
    gemm2_mfma<<<(N_NODES + 127) / 128, 256, 0, stream>>>(H0, W2T, support1, N_NODES);
    spmm2_softmax_kernel<<<N_NODES / 4, 256, 0, stream>>>(support1, row_ptr, pk, b2, out);
}

// Round 5
// 734.510 us; speedup vs baseline: 2.2769x; 1.0357x over previous
//
#include <hip/hip_runtime.h>
#include <hip/hip_bf16.h>

// ---------------- problem constants (match reference) ----------------
static constexpr int N_NODES = 100000;
static constexpr int N_EDGES = 3200000;
static constexpr int NFEAT   = 512;
static constexpr int NHID    = 256;
static constexpr int NCLASS  = 64;

static constexpr int SCAN_CHUNK = 2048;                       // 256 thr * 8 items
static constexpr int NB = (N_NODES + SCAN_CHUNK - 1) / SCAN_CHUNK; // 49

// dst-partitioned CSR build (XCD-local writes/atomics)
static constexpr int PARTS = 8;
static constexpr int NODES_PER_PART = N_NODES / PARTS;         // 12500
static constexpr int EDGES_PER_BLOCK = 1024;                   // 256 thr * 4
static constexpr int NCHUNK = N_EDGES / EDGES_PER_BLOCK;       // 3125

using short8 = __attribute__((ext_vector_type(8))) short;
using f32x4  = __attribute__((ext_vector_type(4))) float;
using fv4    = __attribute__((ext_vector_type(4))) float;

__device__ __forceinline__ float to_f32(float v) { return v; }
__device__ __forceinline__ float to_f32(__hip_bfloat16 v) { return __bfloat162float(v); }

__device__ __forceinline__ short f2bf_bits(float f) {
    __hip_bfloat16 h = __float2bfloat16(f);
    return *reinterpret_cast<short*>(&h);
}

__device__ __forceinline__ float bfbits2f(short b) {
    unsigned u = ((unsigned)(unsigned short)b) << 16;
    return __int_as_float(u);
}

#define GLOBAL_TO_LDS(gsrc, ldst)                                                        \
    __builtin_amdgcn_global_load_lds((const __attribute__((address_space(1))) void*)(gsrc), \
                                     (__attribute__((address_space(3))) void*)(ldst), 16, 0, 0)

// ---------------- CSR build (dst-partitioned) ----------------
__global__ __launch_bounds__(256) void hist_part_kernel(const int* __restrict__ edst,
                                                        int* __restrict__ counts) {
    int p = blockIdx.x & (PARTS - 1);
    int chunk = blockIdx.x >> 3;
    int e0 = chunk * EDGES_PER_BLOCK + threadIdx.x * 4;
    int lo = p * NODES_PER_PART, hi = lo + NODES_PER_PART;
    int4 d4 = *(const int4*)(edst + e0);
    int dd[4] = {d4.x, d4.y, d4.z, d4.w};
#pragma unroll
    for (int k = 0; k < 4; ++k)
        if (dd[k] >= lo && dd[k] < hi) atomicAdd(&counts[dd[k]], 1);
}

__global__ __launch_bounds__(256) void scan_part_kernel(const int* __restrict__ counts,
                                                        int* __restrict__ partials) {
    int b = blockIdx.x, t = threadIdx.x;
    int base = b * SCAN_CHUNK + t * 8;
    int s = 0;
#pragma unroll
    for (int j = 0; j < 8; ++j) {
        int i = base + j;
        if (i < N_NODES) s += counts[i];
    }
    __shared__ int sd[256];
    sd[t] = s;
    __syncthreads();
    for (int off = 128; off > 0; off >>= 1) {
        if (t < off) sd[t] += sd[t + off];
        __syncthreads();
    }
    if (t == 0) partials[b] = sd[0];
}

__global__ void scan_mid_kernel(int* __restrict__ partials) {
    if (threadIdx.x == 0) {
        int run = 0;
        for (int i = 0; i < NB; ++i) {
            int v = partials[i];
            partials[i] = run;
            run += v;
        }
    }
}

__global__ __launch_bounds__(256) void scan_final_kernel(int* __restrict__ counts_cursor,
                                                         int* __restrict__ row_ptr,
                                                         const int* __restrict__ partials) {
    int b = blockIdx.x, t = threadIdx.x;
    int base = b * SCAN_CHUNK + t * 8;
    int v[8];
    int tsum = 0;
#pragma unroll
    for (int j = 0; j < 8; ++j) {
        int i = base + j;
        v[j] = (i < N_NODES) ? counts_cursor[i] : 0;
        tsum += v[j];
    }
    __shared__ int sd[256];
    sd[t] = tsum;
    __syncthreads();
    for (int off = 1; off < 256; off <<= 1) {
        int x = (t >= off) ? sd[t - off] : 0;
        __syncthreads();
        sd[t] += x;
        __syncthreads();
    }
    int run = sd[t] - tsum + partials[b];
#pragma unroll
    for (int j = 0; j < 8; ++j) {
        int i = base + j;
        if (i < N_NODES) {
            row_ptr[i] = run;
            counts_cursor[i] = run;
        }
        run += v[j];
    }
    if (b == 0 && t == 0) row_ptr[N_NODES] = N_EDGES;
}

// partitioned packed scatter: block (chunk, p) stores only edges with dst in partition p.
__global__ __launch_bounds__(256) void scatter_part_kernel(const int* __restrict__ esrc,
                                                           const int* __restrict__ edst,
                                                           const float* __restrict__ ew,
                                                           int* __restrict__ cursor,
                                                           int2* __restrict__ pk) {
    int p = blockIdx.x & (PARTS - 1);
    int chunk = blockIdx.x >> 3;
    int e0 = chunk * EDGES_PER_BLOCK + threadIdx.x * 4;
    int lo = p * NODES_PER_PART, hi = lo + NODES_PER_PART;
    int4 d4 = *(const int4*)(edst + e0);
    int4 s4 = *(const int4*)(esrc + e0);
    float4 w4 = *(const float4*)(ew + e0);
    int   dd[4] = {d4.x, d4.y, d4.z, d4.w};
    int   ss[4] = {s4.x, s4.y, s4.z, s4.w};
    float ww[4] = {w4.x, w4.y, w4.z, w4.w};
#pragma unroll
    for (int k = 0; k < 4; ++k) {
        if (dd[k] >= lo && dd[k] < hi) {
            int pos = atomicAdd(&cursor[dd[k]], 1);
            pk[pos] = make_int2(ss[k], __float_as_int(ww[k]));
        }
    }
}

// ---------------- small transpose+cast: W[K][N] f32 -> WT[N][K] bf16 ----------------
__global__ __launch_bounds__(256) void transpose_w_kernel(const float* __restrict__ W,
                                                          __hip_bfloat16* __restrict__ WT,
                                                          int K, int N) {
    int idx = blockIdx.x * 256 + threadIdx.x;
    if (idx < K * N) {
        int k = idx / N, n = idx % N;
        WT[(size_t)n * K + k] = __float2bfloat16(W[idx]);
    }
}

// ---------------- GEMM1: C[M,256] = A[M,512](f32) @ W1T[256,512](bf16)^T, C bf16 ----
// 128x256 tile (full N in one block: A read exactly once), 4 waves (2x2),
// per-wave 64x128 = 4x8 fragments of 16x16x32 MFMA.
__global__ __launch_bounds__(256) void gemm1_mfma(const float* __restrict__ A,
                                                  const __hip_bfloat16* __restrict__ BT,
                                                  __hip_bfloat16* __restrict__ C,
                                                  int M) {
    constexpr int K = NFEAT;   // 512
    constexpr int N = NHID;    // 256
    constexpr int BM = 128, BN = 256, BK = 32;
    __shared__ __align__(16) __hip_bfloat16 Bs[BN * BK];  // 16 KB
    const int tid = threadIdx.x;
    const int lane = tid & 63, wave = tid >> 6;
    const int wr = wave >> 1, wc = wave & 1;
    const int laneRow = lane & 15, laneK = lane >> 4;
    const int row0 = blockIdx.x * BM;

    f32x4 acc[4][8] = {};

    int arow[4];
#pragma unroll
    for (int i = 0; i < 4; ++i) {
        int r = row0 + wr * 64 + i * 16 + laneRow;
        arow[i] = (r < M) ? r : (M - 1);
    }

    for (int k0 = 0; k0 < K; k0 += BK) {
        // stage B tile: 1024 granules of 16B, swizzle gk ^= (n>>1)&3
#pragma unroll
        for (int it = 0; it < 4; ++it) {
            int idx = tid + it * 256;
            int n = idx >> 2;
            int gk = (idx & 3) ^ ((n >> 1) & 3);
            const __hip_bfloat16* src = BT + (size_t)n * K + k0 + gk * 8;
            GLOBAL_TO_LDS(src, Bs + (size_t)idx * 8);
        }
        // A fragments: 8 consecutive fp32 per lane -> bf16
        short8 af[4];
#pragma unroll
        for (int i = 0; i < 4; ++i) {
            const float* ap = A + (size_t)arow[i] * K + k0 + laneK * 8;
            fv4 a0 = *(const fv4*)ap;
            fv4 a1 = *(const fv4*)(ap + 4);
            short8 v;
#pragma unroll
            for (int j = 0; j < 4; ++j) v[j] = f2bf_bits(a0[j]);
#pragma unroll
            for (int j = 0; j < 4; ++j) v[4 + j] = f2bf_bits(a1[j]);
            af[i] = v;
        }
        __syncthreads();  // drains vmcnt: Bs ready
        short8 bfr[8];
#pragma unroll
        for (int j = 0; j < 8; ++j) {
            int n = wc * 128 + j * 16 + laneRow;
            int pg = laneK ^ ((n >> 1) & 3);
            bfr[j] = *(const short8*)(Bs + n * BK + pg * 8);
        }
#pragma unroll
        for (int i = 0; i < 4; ++i)
#pragma unroll
            for (int j = 0; j < 8; ++j)
                acc[i][j] = __builtin_amdgcn_mfma_f32_16x16x32_bf16(af[i], bfr[j], acc[i][j], 0, 0, 0);
        __syncthreads();  // protect Bs before next stage
    }
#pragma unroll
    for (int i = 0; i < 4; ++i) {
        int rbase = row0 + wr * 64 + i * 16 + laneK * 4;
#pragma unroll
        for (int j = 0; j < 8; ++j) {
            int col = wc * 128 + j * 16 + laneRow;
#pragma unroll
            for (int q = 0; q < 4; ++q) {
                int row = rbase + q;
                if (row < M) C[(size_t)row * N + col] = __float2bfloat16(acc[i][j][q]);
            }
        }
    }
}

// ---------------- GEMM2: C[M,64] = A[M,256](bf16) @ W2T[64,256](bf16)^T, C bf16 ----
__global__ __launch_bounds__(256) void gemm2_mfma(const __hip_bfloat16* __restrict__ A,
                                                  const __hip_bfloat16* __restrict__ BT,
                                                  __hip_bfloat16* __restrict__ C,
                                                  int M) {
    constexpr int K = NHID;    // 256
    constexpr int N = NCLASS;  // 64
    constexpr int BM = 128;
    __shared__ __align__(16) __hip_bfloat16 Bs[N * K];  // 32 KB
    const int tid = threadIdx.x;
    const int lane = tid & 63, wave = tid >> 6;
    const int wr = wave >> 1, wc = wave & 1;
    const int laneRow = lane & 15, laneK = lane >> 4;
    const int row0 = blockIdx.x * BM;

#pragma unroll
    for (int it = 0; it < 8; ++it) {
        int idx = tid + it * 256;
        int n = idx >> 5;
        int kk = (idx & 31) ^ (n & 7);
        const __hip_bfloat16* src = BT + (size_t)n * K + kk * 8;
        GLOBAL_TO_LDS(src, Bs + (size_t)idx * 8);
    }

    int arow[4];
#pragma unroll
    for (int i = 0; i < 4; ++i) {
        int r = row0 + wr * 64 + i * 16 + laneRow;
        arow[i] = (r < M) ? r : (M - 1);
    }

    f32x4 acc[4][2] = {};
    __syncthreads();

#pragma unroll
    for (int k0 = 0; k0 < K; k0 += 32) {
        short8 af[4];
#pragma unroll
        for (int i = 0; i < 4; ++i)
            af[i] = *(const short8*)(A + (size_t)arow[i] * K + k0 + laneK * 8);
        short8 bfr[2];
#pragma unroll
        for (int j = 0; j < 2; ++j) {
            int n = wc * 32 + j * 16 + laneRow;
            int kkw = (k0 >> 3) + laneK;
            int pkk = kkw ^ (n & 7);
            bfr[j] = *(const short8*)(Bs + (size_t)n * 32 * 8 + pkk * 8);
        }
#pragma unroll
        for (int i = 0; i < 4; ++i)
#pragma unroll
            for (int j = 0; j < 2; ++j)
                acc[i][j] = __builtin_amdgcn_mfma_f32_16x16x32_bf16(af[i], bfr[j], acc[i][j], 0, 0, 0);
    }

#pragma unroll
    for (int i = 0; i < 4; ++i) {
        int rbase = row0 + wr * 64 + i * 16 + laneK * 4;
#pragma unroll
        for (int j = 0; j < 2; ++j) {
            int col = wc * 32 + j * 16 + laneRow;
#pragma unroll
            for (int q = 0; q < 4; ++q) {
                int row = rbase + q;
                if (row < M) C[(size_t)row * N + col] = __float2bfloat16(acc[i][j][q]);
            }
        }
    }
}

// ---------------- SPMM layer1: one node per wave, 4 edge slots x 16 chunks,
// gridDim.y = 2 column halves, x2 unrolled (8 gathers in flight per wave) -------------
__global__ __launch_bounds__(256) void spmm1_kernel(const __hip_bfloat16* __restrict__ support0,
                                                    const int* __restrict__ row_ptr,
                                                    const int2* __restrict__ pk,
                                                    const float* __restrict__ b1,
                                                    __hip_bfloat16* __restrict__ H0) {
    int node = blockIdx.x * 4 + (threadIdx.x >> 6);
    int lane = threadIdx.x & 63;
    int j = lane >> 4;                 // edge slot 0..3
    int c = lane & 15;                 // column chunk (8 cols each) -> 128 cols
    int coff = blockIdx.y * 128 + c * 8;
    int beg = row_ptr[node], end = row_ptr[node + 1];
    float acc[8] = {};
    for (int base = beg; base + j < end; base += 8) {
        int2 pe0 = pk[base + j];
        int i1 = base + 4 + j;
        int2 pe1 = (i1 < end) ? pk[i1] : make_int2(0, 0);
        float w0 = __int_as_float(pe0.y);
        float w1 = __int_as_float(pe1.y);
        short8 v0 = *(const short8*)(support0 + (size_t)pe0.x * NHID + coff);
        short8 v1 = *(const short8*)(support0 + (size_t)pe1.x * NHID + coff);
#pragma unroll
        for (int k = 0; k < 8; ++k) acc[k] += w0 * bfbits2f(v0[k]);
#pragma unroll
        for (int k = 0; k < 8; ++k) acc[k] += w1 * bfbits2f(v1[k]);
    }
#pragma unroll
    for (int k = 0; k < 8; ++k) {
        acc[k] += __shfl_xor(acc[k], 16);
        acc[k] += __shfl_xor(acc[k], 32);
    }
    if (lane < 16) {
        fv4 blo = *(const fv4*)(b1 + coff);
        fv4 bhi = *(const fv4*)(b1 + coff + 4);
        short8 o;
#pragma unroll
        for (int k = 0; k < 4; ++k) o[k] = f2bf_bits(fmaxf(acc[k] + blo[k], 0.f));
#pragma unroll
        for (int k = 0; k < 4; ++k) o[4 + k] = f2bf_bits(fmaxf(acc[4 + k] + bhi[k], 0.f));
        *(short8*)(H0 + (size_t)node * NHID + coff) = o;
    }
}

// ---------------- SPMM layer2 + bias + log_softmax (8 slots x 8 chunks, x2 unroll) ---
__global__ __launch_bounds__(256) void spmm2_softmax_kernel(const __hip_bfloat16* __restrict__ support1,
                                                            const int* __restrict__ row_ptr,
                                                            const int2* __restrict__ pk,
                                                            const float* __restrict__ b2,
                                                            float* __restrict__ out) {
    int node = blockIdx.x * 4 + (threadIdx.x >> 6);
    int lane = threadIdx.x & 63;
    int j = lane >> 3;   // edge slot 0..7
    int c = lane & 7;    // class chunk (8 classes each)
    int beg = row_ptr[node], end = row_ptr[node + 1];
    float acc[8] = {};
    for (int base = beg; base + j < end; base += 16) {
        int2 pe0 = pk[base + j];
        int i1 = base + 8 + j;
        int2 pe1 = (i1 < end) ? pk[i1] : make_int2(0, 0);
        float w0 = __int_as_float(pe0.y);
        float w1 = __int_as_float(pe1.y);
        short8 v0 = *(const short8*)(support1 + (size_t)pe0.x * NCLASS + c * 8);
        short8 v1 = *(const short8*)(support1 + (size_t)pe1.x * NCLASS + c * 8);
#pragma unroll
        for (int k = 0; k < 8; ++k) acc[k] += w0 * bfbits2f(v0[k]);
#pragma unroll
        for (int k = 0; k < 8; ++k) acc[k] += w1 * bfbits2f(v1[k]);
    }
#pragma unroll
    for (int m = 8; m < 64; m <<= 1)
#pragma unroll
        for (int k = 0; k < 8; ++k) acc[k] += __shfl_xor(acc[k], m);

    fv4 blo = *(const fv4*)(b2 + c * 8);
    fv4 bhi = *(const fv4*)(b2 + c * 8 + 4);
    float z[8];
#pragma unroll
    for (int k = 0; k < 4; ++k) z[k] = acc[k] + blo[k];
#pragma unroll
    for (int k = 0; k < 4; ++k) z[4 + k] = acc[4 + k] + bhi[k];

    float mx = z[0];
#pragma unroll
    for (int k = 1; k < 8; ++k) mx = fmaxf(mx, z[k]);
#pragma unroll
    for (int m = 1; m < 8; m <<= 1) mx = fmaxf(mx, __shfl_xor(mx, m));
    float s = 0.f;
#pragma unroll
    for (int k = 0; k < 8; ++k) s += __expf(z[k] - mx);
#pragma unroll
    for (int m = 1; m < 8; m <<= 1) s += __shfl_xor(s, m);
    float lg = __logf(s);
    if (lane < 8) {
        f32x4 o0, o1;
#pragma unroll
        for (int k = 0; k < 4; ++k) o0[k] = z[k] - mx - lg;
#pragma unroll
        for (int k = 0; k < 4; ++k) o1[k] = z[4 + k] - mx - lg;
        float* dst = out + (size_t)node * NCLASS + c * 8;
        *(f32x4*)dst = o0;
        *(f32x4*)(dst + 4) = o1;
    }
}

// ---------------- host launch ----------------
extern "C" void kernel_launch(void* const* d_in, const int* in_sizes, int n_in,
                              void* d_out, int out_size, void* d_ws, size_t ws_size,
                              hipStream_t stream) {
    const float* x    = (const float*)d_in[0];
    const int*   esrc = (const int*)d_in[1];
    const int*   edst = (const int*)d_in[2];
    const float* ew   = (const float*)d_in[3];
    const float* W1   = (const float*)d_in[4];
    const float* b1   = (const float*)d_in[5];
    const float* W2   = (const float*)d_in[6];
    const float* b2   = (const float*)d_in[7];
    float* out = (float*)d_out;

    char* ws = (char*)d_ws;
    size_t off = 0;
    auto alloc = [&](size_t bytes) {
        size_t o = off;
        off = (off + bytes + 255) & ~(size_t)255;
        return o;
    };
    __hip_bfloat16* support0 = (__hip_bfloat16*)(ws + alloc((size_t)N_NODES * NHID * 2));
    __hip_bfloat16* H0       = (__hip_bfloat16*)(ws + alloc((size_t)N_NODES * NHID * 2));
    __hip_bfloat16* support1 = (__hip_bfloat16*)(ws + alloc((size_t)N_NODES * NCLASS * 2));
    int2*  pk         = (int2*)(ws + alloc((size_t)N_EDGES * 8));
    int*   row_ptr    = (int*)(ws + alloc((size_t)(N_NODES + 1) * 4));
    int*   cursor     = (int*)(ws + alloc((size_t)N_NODES * 4));
    int*   partials   = (int*)(ws + alloc(256 * 4));
    __hip_bfloat16* W1T = (__hip_bfloat16*)(ws + alloc((size_t)NHID * NFEAT * 2));
    __hip_bfloat16* W2T = (__hip_bfloat16*)(ws + alloc((size_t)NCLASS * NHID * 2));

    // --- weight transposes (bf16) ---
    transpose_w_kernel<<<(NFEAT * NHID + 255) / 256, 256, 0, stream>>>(W1, W1T, NFEAT, NHID);
    transpose_w_kernel<<<(NHID * NCLASS + 255) / 256, 256, 0, stream>>>(W2, W2T, NHID, NCLASS);

    // --- CSR build (dst-partitioned: partition = blockIdx & 7 -> XCD-local L2) ---
    hipMemsetAsync(cursor, 0, (size_t)N_NODES * 4, stream);
    hist_part_kernel<<<NCHUNK * PARTS, 256, 0, stream>>>(edst, cursor);
    scan_part_kernel<<<NB, 256, 0, stream>>>(cursor, partials);
    scan_mid_kernel<<<1, 64, 0, stream>>>(partials);
    scan_final_kernel<<<NB, 256, 0, stream>>>(cursor, row_ptr, partials);
    scatter_part_kernel<<<NCHUNK * PARTS, 256, 0, stream>>>(esrc, edst, ew, cursor, pk);

    // --- Layer 1 ---
    gemm1_mfma<<<(N_NODES + 127) / 128, 256, 0, stream>>>(x, W1T, support0, N_NODES);
    spmm1_kernel<<<dim3(N_NODES / 4, 2), 256, 0, stream>>>(support0, row_ptr, pk, b1, H0);

    // --- Layer 2 ---
    gemm2_mfma<<<(N_NODES + 127) / 128, 256, 0, stream>>>(H0, W2T, support1, N_NODES);
    spmm2_softmax_kernel<<<N_NODES / 4, 256, 0, stream>>>(support1, row_ptr, pk, b2, out);
}

// Round 6
// 664.414 us; speedup vs baseline: 2.5171x; 1.1055x over previous
//
#include <hip/hip_runtime.h>
#include <hip/hip_bf16.h>

// ---------------- problem constants (match reference) ----------------
static constexpr int N_NODES = 100000;
static constexpr int N_EDGES = 3200000;
static constexpr int NFEAT   = 512;
static constexpr int NHID    = 256;
static constexpr int NCLASS  = 64;

static constexpr int SCAN_CHUNK = 2048;                       // 256 thr * 8 items
static constexpr int NB = (N_NODES + SCAN_CHUNK - 1) / SCAN_CHUNK; // 49

// dst-partitioned CSR build (XCD-local writes/atomics)
static constexpr int PARTS = 8;
static constexpr int NODES_PER_PART = N_NODES / PARTS;         // 12500
static constexpr int EDGES_PER_BLOCK = 1024;                   // 256 thr * 4
static constexpr int NCHUNK = N_EDGES / EDGES_PER_BLOCK;       // 3125

using short8 = __attribute__((ext_vector_type(8))) short;
using f32x4  = __attribute__((ext_vector_type(4))) float;
using fv4    = __attribute__((ext_vector_type(4))) float;
using fv2    = __attribute__((ext_vector_type(2))) float;

__device__ __forceinline__ float to_f32(float v) { return v; }
__device__ __forceinline__ float to_f32(__hip_bfloat16 v) { return __bfloat162float(v); }

__device__ __forceinline__ short f2bf_bits(float f) {
    __hip_bfloat16 h = __float2bfloat16(f);
    return *reinterpret_cast<short*>(&h);
}

__device__ __forceinline__ float bfbits2f(short b) {
    unsigned u = ((unsigned)(unsigned short)b) << 16;
    return __int_as_float(u);
}

// fp8 (OCP e4m3) helpers — gfx950 v_cvt_pk_* instructions
__device__ __forceinline__ unsigned char f2fp8(float v) {
    int p = __builtin_amdgcn_cvt_pk_fp8_f32(v, v, 0, false);
    return (unsigned char)(p & 0xff);
}

// accumulate acc[k] += w * fp8[k] for 8 packed fp8 values in (vx, vy)
__device__ __forceinline__ void fp8x8_acc(int vx, int vy, float w, float* acc) {
    fv2 a0 = __builtin_amdgcn_cvt_pk_f32_fp8(vx, false);
    fv2 a1 = __builtin_amdgcn_cvt_pk_f32_fp8(vx, true);
    fv2 a2 = __builtin_amdgcn_cvt_pk_f32_fp8(vy, false);
    fv2 a3 = __builtin_amdgcn_cvt_pk_f32_fp8(vy, true);
    acc[0] += w * a0[0]; acc[1] += w * a0[1];
    acc[2] += w * a1[0]; acc[3] += w * a1[1];
    acc[4] += w * a2[0]; acc[5] += w * a2[1];
    acc[6] += w * a3[0]; acc[7] += w * a3[1];
}

#define GLOBAL_TO_LDS(gsrc, ldst)                                                        \
    __builtin_amdgcn_global_load_lds((const __attribute__((address_space(1))) void*)(gsrc), \
                                     (__attribute__((address_space(3))) void*)(ldst), 16, 0, 0)

// ---------------- CSR build (dst-partitioned) ----------------
__global__ __launch_bounds__(256) void hist_part_kernel(const int* __restrict__ edst,
                                                        int* __restrict__ counts) {
    int p = blockIdx.x & (PARTS - 1);
    int chunk = blockIdx.x >> 3;
    int e0 = chunk * EDGES_PER_BLOCK + threadIdx.x * 4;
    int lo = p * NODES_PER_PART, hi = lo + NODES_PER_PART;
    int4 d4 = *(const int4*)(edst + e0);
    int dd[4] = {d4.x, d4.y, d4.z, d4.w};
#pragma unroll
    for (int k = 0; k < 4; ++k)
        if (dd[k] >= lo && dd[k] < hi) atomicAdd(&counts[dd[k]], 1);
}

__global__ __launch_bounds__(256) void scan_part_kernel(const int* __restrict__ counts,
                                                        int* __restrict__ partials) {
    int b = blockIdx.x, t = threadIdx.x;
    int base = b * SCAN_CHUNK + t * 8;
    int s = 0;
#pragma unroll
    for (int j = 0; j < 8; ++j) {
        int i = base + j;
        if (i < N_NODES) s += counts[i];
    }
    __shared__ int sd[256];
    sd[t] = s;
    __syncthreads();
    for (int off = 128; off > 0; off >>= 1) {
        if (t < off) sd[t] += sd[t + off];
        __syncthreads();
    }
    if (t == 0) partials[b] = sd[0];
}

__global__ void scan_mid_kernel(int* __restrict__ partials) {
    if (threadIdx.x == 0) {
        int run = 0;
        for (int i = 0; i < NB; ++i) {
            int v = partials[i];
            partials[i] = run;
            run += v;
        }
    }
}

__global__ __launch_bounds__(256) void scan_final_kernel(int* __restrict__ counts_cursor,
                                                         int* __restrict__ row_ptr,
                                                         const int* __restrict__ partials) {
    int b = blockIdx.x, t = threadIdx.x;
    int base = b * SCAN_CHUNK + t * 8;
    int v[8];
    int tsum = 0;
#pragma unroll
    for (int j = 0; j < 8; ++j) {
        int i = base + j;
        v[j] = (i < N_NODES) ? counts_cursor[i] : 0;
        tsum += v[j];
    }
    __shared__ int sd[256];
    sd[t] = tsum;
    __syncthreads();
    for (int off = 1; off < 256; off <<= 1) {
        int x = (t >= off) ? sd[t - off] : 0;
        __syncthreads();
        sd[t] += x;
        __syncthreads();
    }
    int run = sd[t] - tsum + partials[b];
#pragma unroll
    for (int j = 0; j < 8; ++j) {
        int i = base + j;
        if (i < N_NODES) {
            row_ptr[i] = run;
            counts_cursor[i] = run;
        }
        run += v[j];
    }
    if (b == 0 && t == 0) row_ptr[N_NODES] = N_EDGES;
}

// partitioned packed scatter: block (chunk, p) stores only edges with dst in partition p.
__global__ __launch_bounds__(256) void scatter_part_kernel(const int* __restrict__ esrc,
                                                           const int* __restrict__ edst,
                                                           const float* __restrict__ ew,
                                                           int* __restrict__ cursor,
                                                           int2* __restrict__ pk) {
    int p = blockIdx.x & (PARTS - 1);
    int chunk = blockIdx.x >> 3;
    int e0 = chunk * EDGES_PER_BLOCK + threadIdx.x * 4;
    int lo = p * NODES_PER_PART, hi = lo + NODES_PER_PART;
    int4 d4 = *(const int4*)(edst + e0);
    int4 s4 = *(const int4*)(esrc + e0);
    float4 w4 = *(const float4*)(ew + e0);
    int   dd[4] = {d4.x, d4.y, d4.z, d4.w};
    int   ss[4] = {s4.x, s4.y, s4.z, s4.w};
    float ww[4] = {w4.x, w4.y, w4.z, w4.w};
#pragma unroll
    for (int k = 0; k < 4; ++k) {
        if (dd[k] >= lo && dd[k] < hi) {
            int pos = atomicAdd(&cursor[dd[k]], 1);
            pk[pos] = make_int2(ss[k], __float_as_int(ww[k]));
        }
    }
}

// ---------------- small transpose+cast: W[K][N] f32 -> WT[N][K] bf16 ----------------
__global__ __launch_bounds__(256) void transpose_w_kernel(const float* __restrict__ W,
                                                          __hip_bfloat16* __restrict__ WT,
                                                          int K, int N) {
    int idx = blockIdx.x * 256 + threadIdx.x;
    if (idx < K * N) {
        int k = idx / N, n = idx % N;
        WT[(size_t)n * K + k] = __float2bfloat16(W[idx]);
    }
}

// ---------------- GEMM1: support0[M,256](fp8) = A[M,512](f32) @ W1T[256,512]^T -------
// 128x256 tile (full N in one block: A read exactly once), 4 waves (2x2),
// per-wave 64x128 = 4x8 fragments of 16x16x32 MFMA. fp8 epilogue.
__global__ __launch_bounds__(256) void gemm1_mfma(const float* __restrict__ A,
                                                  const __hip_bfloat16* __restrict__ BT,
                                                  unsigned char* __restrict__ C8,
                                                  int M) {
    constexpr int K = NFEAT;   // 512
    constexpr int N = NHID;    // 256
    constexpr int BM = 128, BN = 256, BK = 32;
    __shared__ __align__(16) __hip_bfloat16 Bs[BN * BK];  // 16 KB
    const int tid = threadIdx.x;
    const int lane = tid & 63, wave = tid >> 6;
    const int wr = wave >> 1, wc = wave & 1;
    const int laneRow = lane & 15, laneK = lane >> 4;
    const int row0 = blockIdx.x * BM;

    f32x4 acc[4][8] = {};

    int arow[4];
#pragma unroll
    for (int i = 0; i < 4; ++i) {
        int r = row0 + wr * 64 + i * 16 + laneRow;
        arow[i] = (r < M) ? r : (M - 1);
    }

    for (int k0 = 0; k0 < K; k0 += BK) {
#pragma unroll
        for (int it = 0; it < 4; ++it) {
            int idx = tid + it * 256;
            int n = idx >> 2;
            int gk = (idx & 3) ^ ((n >> 1) & 3);
            const __hip_bfloat16* src = BT + (size_t)n * K + k0 + gk * 8;
            GLOBAL_TO_LDS(src, Bs + (size_t)idx * 8);
        }
        short8 af[4];
#pragma unroll
        for (int i = 0; i < 4; ++i) {
            const float* ap = A + (size_t)arow[i] * K + k0 + laneK * 8;
            fv4 a0 = *(const fv4*)ap;
            fv4 a1 = *(const fv4*)(ap + 4);
            short8 v;
#pragma unroll
            for (int j = 0; j < 4; ++j) v[j] = f2bf_bits(a0[j]);
#pragma unroll
            for (int j = 0; j < 4; ++j) v[4 + j] = f2bf_bits(a1[j]);
            af[i] = v;
        }
        __syncthreads();  // drains vmcnt: Bs ready
        short8 bfr[8];
#pragma unroll
        for (int j = 0; j < 8; ++j) {
            int n = wc * 128 + j * 16 + laneRow;
            int pg = laneK ^ ((n >> 1) & 3);
            bfr[j] = *(const short8*)(Bs + n * BK + pg * 8);
        }
#pragma unroll
        for (int i = 0; i < 4; ++i)
#pragma unroll
            for (int j = 0; j < 8; ++j)
                acc[i][j] = __builtin_amdgcn_mfma_f32_16x16x32_bf16(af[i], bfr[j], acc[i][j], 0, 0, 0);
        __syncthreads();  // protect Bs before next stage
    }
#pragma unroll
    for (int i = 0; i < 4; ++i) {
        int rbase = row0 + wr * 64 + i * 16 + laneK * 4;
#pragma unroll
        for (int j = 0; j < 8; ++j) {
            int col = wc * 128 + j * 16 + laneRow;
#pragma unroll
            for (int q = 0; q < 4; ++q) {
                int row = rbase + q;
                if (row < M) C8[(size_t)row * N + col] = f2fp8(acc[i][j][q]);
            }
        }
    }
}

// ---------------- GEMM2: support1[M,64](fp8) = H0[M,256](bf16) @ W2T[64,256]^T ------
__global__ __launch_bounds__(256) void gemm2_mfma(const __hip_bfloat16* __restrict__ A,
                                                  const __hip_bfloat16* __restrict__ BT,
                                                  unsigned char* __restrict__ C8,
                                                  int M) {
    constexpr int K = NHID;    // 256
    constexpr int N = NCLASS;  // 64
    constexpr int BM = 128;
    __shared__ __align__(16) __hip_bfloat16 Bs[N * K];  // 32 KB
    const int tid = threadIdx.x;
    const int lane = tid & 63, wave = tid >> 6;
    const int wr = wave >> 1, wc = wave & 1;
    const int laneRow = lane & 15, laneK = lane >> 4;
    const int row0 = blockIdx.x * BM;

#pragma unroll
    for (int it = 0; it < 8; ++it) {
        int idx = tid + it * 256;
        int n = idx >> 5;
        int kk = (idx & 31) ^ (n & 7);
        const __hip_bfloat16* src = BT + (size_t)n * K + kk * 8;
        GLOBAL_TO_LDS(src, Bs + (size_t)idx * 8);
    }

    int arow[4];
#pragma unroll
    for (int i = 0; i < 4; ++i) {
        int r = row0 + wr * 64 + i * 16 + laneRow;
        arow[i] = (r < M) ? r : (M - 1);
    }

    f32x4 acc[4][2] = {};
    __syncthreads();

#pragma unroll
    for (int k0 = 0; k0 < K; k0 += 32) {
        short8 af[4];
#pragma unroll
        for (int i = 0; i < 4; ++i)
            af[i] = *(const short8*)(A + (size_t)arow[i] * K + k0 + laneK * 8);
        short8 bfr[2];
#pragma unroll
        for (int j = 0; j < 2; ++j) {
            int n = wc * 32 + j * 16 + laneRow;
            int kkw = (k0 >> 3) + laneK;
            int pkk = kkw ^ (n & 7);
            bfr[j] = *(const short8*)(Bs + (size_t)n * 32 * 8 + pkk * 8);
        }
#pragma unroll
        for (int i = 0; i < 4; ++i)
#pragma unroll
            for (int j = 0; j < 2; ++j)
                acc[i][j] = __builtin_amdgcn_mfma_f32_16x16x32_bf16(af[i], bfr[j], acc[i][j], 0, 0, 0);
    }

#pragma unroll
    for (int i = 0; i < 4; ++i) {
        int rbase = row0 + wr * 64 + i * 16 + laneK * 4;
#pragma unroll
        for (int j = 0; j < 2; ++j) {
            int col = wc * 32 + j * 16 + laneRow;
#pragma unroll
            for (int q = 0; q < 4; ++q) {
                int row = rbase + q;
                if (row < M) C8[(size_t)row * N + col] = f2fp8(acc[i][j][q]);
            }
        }
    }
}

// ---------------- SPMM layer1: fp8 gather, one node per wave, 4 slots x 16 chunks,
// gridDim.y = 2 column halves, x2 unrolled (8 gathers in flight per wave) -------------
__global__ __launch_bounds__(256) void spmm1_kernel(const unsigned char* __restrict__ s0_8,
                                                    const int* __restrict__ row_ptr,
                                                    const int2* __restrict__ pk,
                                                    const float* __restrict__ b1,
                                                    __hip_bfloat16* __restrict__ H0) {
    int node = blockIdx.x * 4 + (threadIdx.x >> 6);
    int lane = threadIdx.x & 63;
    int j = lane >> 4;                 // edge slot 0..3
    int c = lane & 15;                 // column chunk (8 cols each) -> 128 cols
    int coff = blockIdx.y * 128 + c * 8;
    int beg = row_ptr[node], end = row_ptr[node + 1];
    float acc[8] = {};
    for (int base = beg; base + j < end; base += 8) {
        int2 pe0 = pk[base + j];
        int i1 = base + 4 + j;
        int2 pe1 = (i1 < end) ? pk[i1] : make_int2(0, 0);
        float w0 = __int_as_float(pe0.y);
        float w1 = __int_as_float(pe1.y);
        int2 v0 = *(const int2*)(s0_8 + (size_t)pe0.x * NHID + coff);
        int2 v1 = *(const int2*)(s0_8 + (size_t)pe1.x * NHID + coff);
        fp8x8_acc(v0.x, v0.y, w0, acc);
        fp8x8_acc(v1.x, v1.y, w1, acc);
    }
#pragma unroll
    for (int k = 0; k < 8; ++k) {
        acc[k] += __shfl_xor(acc[k], 16);
        acc[k] += __shfl_xor(acc[k], 32);
    }
    if (lane < 16) {
        fv4 blo = *(const fv4*)(b1 + coff);
        fv4 bhi = *(const fv4*)(b1 + coff + 4);
        short8 o;
#pragma unroll
        for (int k = 0; k < 4; ++k) o[k] = f2bf_bits(fmaxf(acc[k] + blo[k], 0.f));
#pragma unroll
        for (int k = 0; k < 4; ++k) o[4 + k] = f2bf_bits(fmaxf(acc[4 + k] + bhi[k], 0.f));
        *(short8*)(H0 + (size_t)node * NHID + coff) = o;
    }
}

// ---------------- SPMM layer2 + bias + log_softmax (fp8 gather, 8x8, x2 unroll) ------
__global__ __launch_bounds__(256) void spmm2_softmax_kernel(const unsigned char* __restrict__ s1_8,
                                                            const int* __restrict__ row_ptr,
                                                            const int2* __restrict__ pk,
                                                            const float* __restrict__ b2,
                                                            float* __restrict__ out) {
    int node = blockIdx.x * 4 + (threadIdx.x >> 6);
    int lane = threadIdx.x & 63;
    int j = lane >> 3;   // edge slot 0..7
    int c = lane & 7;    // class chunk (8 classes each)
    int beg = row_ptr[node], end = row_ptr[node + 1];
    float acc[8] = {};
    for (int base = beg; base + j < end; base += 16) {
        int2 pe0 = pk[base + j];
        int i1 = base + 8 + j;
        int2 pe1 = (i1 < end) ? pk[i1] : make_int2(0, 0);
        float w0 = __int_as_float(pe0.y);
        float w1 = __int_as_float(pe1.y);
        int2 v0 = *(const int2*)(s1_8 + (size_t)pe0.x * NCLASS + c * 8);
        int2 v1 = *(const int2*)(s1_8 + (size_t)pe1.x * NCLASS + c * 8);
        fp8x8_acc(v0.x, v0.y, w0, acc);
        fp8x8_acc(v1.x, v1.y, w1, acc);
    }
#pragma unroll
    for (int m = 8; m < 64; m <<= 1)
#pragma unroll
        for (int k = 0; k < 8; ++k) acc[k] += __shfl_xor(acc[k], m);

    fv4 blo = *(const fv4*)(b2 + c * 8);
    fv4 bhi = *(const fv4*)(b2 + c * 8 + 4);
    float z[8];
#pragma unroll
    for (int k = 0; k < 4; ++k) z[k] = acc[k] + blo[k];
#pragma unroll
    for (int k = 0; k < 4; ++k) z[4 + k] = acc[4 + k] + bhi[k];

    float mx = z[0];
#pragma unroll
    for (int k = 1; k < 8; ++k) mx = fmaxf(mx, z[k]);
#pragma unroll
    for (int m = 1; m < 8; m <<= 1) mx = fmaxf(mx, __shfl_xor(mx, m));
    float s = 0.f;
#pragma unroll
    for (int k = 0; k < 8; ++k) s += __expf(z[k] - mx);
#pragma unroll
    for (int m = 1; m < 8; m <<= 1) s += __shfl_xor(s, m);
    float lg = __logf(s);
    if (lane < 8) {
        f32x4 o0, o1;
#pragma unroll
        for (int k = 0; k < 4; ++k) o0[k] = z[k] - mx - lg;
#pragma unroll
        for (int k = 0; k < 4; ++k) o1[k] = z[4 + k] - mx - lg;
        float* dst = out + (size_t)node * NCLASS + c * 8;
        *(f32x4*)dst = o0;
        *(f32x4*)(dst + 4) = o1;
    }
}

// ---------------- host launch ----------------
extern "C" void kernel_launch(void* const* d_in, const int* in_sizes, int n_in,
                              void* d_out, int out_size, void* d_ws, size_t ws_size,
                              hipStream_t stream) {
    const float* x    = (const float*)d_in[0];
    const int*   esrc = (const int*)d_in[1];
    const int*   edst = (const int*)d_in[2];
    const float* ew   = (const float*)d_in[3];
    const float* W1   = (const float*)d_in[4];
    const float* b1   = (const float*)d_in[5];
    const float* W2   = (const float*)d_in[6];
    const float* b2   = (const float*)d_in[7];
    float* out = (float*)d_out;

    char* ws = (char*)d_ws;
    size_t off = 0;
    auto alloc = [&](size_t bytes) {
        size_t o = off;
        off = (off + bytes + 255) & ~(size_t)255;
        return o;
    };
    unsigned char* support0 = (unsigned char*)(ws + alloc((size_t)N_NODES * NHID));
    __hip_bfloat16* H0      = (__hip_bfloat16*)(ws + alloc((size_t)N_NODES * NHID * 2));
    unsigned char* support1 = (unsigned char*)(ws + alloc((size_t)N_NODES * NCLASS));
    int2*  pk         = (int2*)(ws + alloc((size_t)N_EDGES * 8));
    int*   row_ptr    = (int*)(ws + alloc((size_t)(N_NODES + 1) * 4));
    int*   cursor     = (int*)(ws + alloc((size_t)N_NODES * 4));
    int*   partials   = (int*)(ws + alloc(256 * 4));
    __hip_bfloat16* W1T = (__hip_bfloat16*)(ws + alloc((size_t)NHID * NFEAT * 2));
    __hip_bfloat16* W2T = (__hip_bfloat16*)(ws + alloc((size_t)NCLASS * NHID * 2));

    // --- weight transposes (bf16) ---
    transpose_w_kernel<<<(NFEAT * NHID + 255) / 256, 256, 0, stream>>>(W1, W1T, NFEAT, NHID);
    transpose_w_kernel<<<(NHID * NCLASS + 255) / 256, 256, 0, stream>>>(W2, W2T, NHID, NCLASS);

    // --- CSR build (dst-partitioned: partition = blockIdx & 7 -> XCD-local L2) ---
    hipMemsetAsync(cursor, 0, (size_t)N_NODES * 4, stream);
    hist_part_kernel<<<NCHUNK * PARTS, 256, 0, stream>>>(edst, cursor);
    scan_part_kernel<<<NB, 256, 0, stream>>>(cursor, partials);
    scan_mid_kernel<<<1, 64, 0, stream>>>(partials);
    scan_final_kernel<<<NB, 256, 0, stream>>>(cursor, row_ptr, partials);
    scatter_part_kernel<<<NCHUNK * PARTS, 256, 0, stream>>>(esrc, edst, ew, cursor, pk);

    // --- Layer 1 ---
    gemm1_mfma<<<(N_NODES + 127) / 128, 256, 0, stream>>>(x, W1T, support0, N_NODES);
    spmm1_kernel<<<dim3(N_NODES / 4, 2), 256, 0, stream>>>(support0, row_ptr, pk, b1, H0);

    // --- Layer 2 ---
    gemm2_mfma<<<(N_NODES + 127) / 128, 256, 0, stream>>>(H0, W2T, support1, N_NODES);
    spmm2_softmax_kernel<<<N_NODES / 4, 256, 0, stream>>>(support1, row_ptr, pk, b2, out);
}